// Round 11
// baseline (2462.318 us; speedup 1.0000x reference)
//
#include <hip/hip_runtime.h>
#include <hip/hip_bf16.h>
#include <math.h>

// ---------------------------------------------------------------------------
// RWKV7 vision block. Pipelined bf16 MFMA GEMMs (3-buf counted-vmcnt) +
// chunked parallel scan (LC=32, 4 blocks/CU): scan1 emits P,Q,y=P*r,o_local;
// scan2 composes chunk states (Sst overwrites Q in place); corr adds
// S_start @ y. B=4, T=1024, C=512, H=8, N=64, L=8.
// ---------------------------------------------------------------------------

#define NTOK 4096
#define CDIM 512
#define TT   1024
#define LC   32
#define NCH  32
#define TB   8      // scan time-steps per LDS stage group

#define BM 128
#define BK 32

enum { EPI_NONE=0, EPI_TANH, EPI_SIG, EPI_DECAY, EPI_SIGB, EPI_VMIX, EPI_RELU2, EPI_ADD };

typedef short bf16x8 __attribute__((ext_vector_type(8)));
typedef float f32x4 __attribute__((ext_vector_type(4)));
typedef unsigned short ushort_t;

__device__ __forceinline__ float wsum64(float v) {
#pragma unroll
  for (int s = 1; s < 64; s <<= 1) v += __shfl_xor(v, s);
  return v;
}
__device__ __forceinline__ float gsum8(float v) {
  v += __shfl_xor(v, 1); v += __shfl_xor(v, 2); v += __shfl_xor(v, 4);
  return v;
}
// Sum over the 16 lanes of a DPP row (all lanes receive the total).
__device__ __forceinline__ float rowsum16(float x) {
  int t;
  t = __builtin_amdgcn_mov_dpp(__builtin_bit_cast(int, x), 0x128, 0xF, 0xF, true); // row_ror:8
  x += __builtin_bit_cast(float, t);
  t = __builtin_amdgcn_mov_dpp(__builtin_bit_cast(int, x), 0x124, 0xF, 0xF, true); // row_ror:4
  x += __builtin_bit_cast(float, t);
  t = __builtin_amdgcn_mov_dpp(__builtin_bit_cast(int, x), 0x122, 0xF, 0xF, true); // row_ror:2
  x += __builtin_bit_cast(float, t);
  t = __builtin_amdgcn_mov_dpp(__builtin_bit_cast(int, x), 0x121, 0xF, 0xF, true); // row_ror:1
  x += __builtin_bit_cast(float, t);
  return x;
}
__device__ __forceinline__ float sigm(float z) { return 1.f / (1.f + expf(-z)); }
__device__ __forceinline__ ushort_t f2bf(float x) {
  return __builtin_bit_cast(unsigned short, __float2bfloat16(x));
}
__device__ __forceinline__ void glds16(const void* g, void* l) {
  __builtin_amdgcn_global_load_lds(
      (const __attribute__((address_space(1))) void*)g,
      (__attribute__((address_space(3))) void*)l, 16, 0, 0);
}

// ---------------------------------------------------------------------------
// Grouped bf16 MFMA GEMM:  C[M,N] = epi(A[M,K] @ B[Npad,K]^T), per-z segment.
// ---------------------------------------------------------------------------
struct Seg {
  const ushort_t* A; const ushort_t* B; void* C;
  const float* bias; const float* e1;
  int N; int K; int epi; int obf;
};
struct Segs4 { Seg s[4]; };

template<int BNt>
__global__ __launch_bounds__(256) void ggemm_k(Segs4 segs) {
  const Seg sg = segs.s[blockIdx.z];
  if (sg.epi < 0) return;
  constexpr int NCHK = 8 + BNt / 16;
  constexpr int LPW  = NCHK / 4;
  constexpr int WNF  = BNt / 32;
  __shared__ ushort_t As[3][BM * BK];
  __shared__ ushort_t Bs[3][BNt * BK];
  const ushort_t* __restrict__ A = sg.A;
  const ushort_t* __restrict__ B = sg.B;
  const int N = sg.N, K = sg.K;
  const int tid = threadIdx.x;
  const int wave = tid >> 6, lane = tid & 63;
  const int m0 = blockIdx.x * BM, n0 = blockIdx.y * BNt;
  const int wm = (wave >> 1) << 6, wn = (wave & 1) * (BNt / 2);

  f32x4 zero = {0.f, 0.f, 0.f, 0.f};
  f32x4 acc[4][WNF];
#pragma unroll
  for (int i = 0; i < 4; ++i)
#pragma unroll
    for (int j = 0; j < WNF; ++j) acc[i][j] = zero;

  const int crow = lane >> 2;
  const int soff = (((lane & 3) ^ (crow & 3)) << 3);
  const ushort_t* gptr[LPW];
  ushort_t* lbase[LPW];
  int lstr[LPW];
#pragma unroll
  for (int i = 0; i < LPW; ++i) {
    const int c = wave + 4 * i;
    if (c < 8) {
      gptr[i] = A + (size_t)(m0 + c * 16 + crow) * K + soff;
      lbase[i] = &As[0][c * 512 + lane * 8];
      lstr[i] = BM * BK;
    } else {
      gptr[i] = B + (size_t)(n0 + (c - 8) * 16 + crow) * K + soff;
      lbase[i] = &Bs[0][(c - 8) * 512 + lane * 8];
      lstr[i] = BNt * BK;
    }
  }

#define STAGE(bf_, k0_)                                        \
  { _Pragma("unroll") for (int i = 0; i < LPW; ++i)            \
      glds16(gptr[i] + (k0_), lbase[i] + (bf_) * lstr[i]); }

  const int rA = wm + (lane & 15);
  const int rB = wn + (lane & 15);
  const int kb = (((lane >> 4) ^ (lane & 3)) << 3);

#define COMPUTE(bf_)                                                          \
  {                                                                           \
    bf16x8 av[4], bvv[WNF];                                                   \
    _Pragma("unroll") for (int f = 0; f < 4; ++f)                             \
      av[f] = *(const bf16x8*)(&As[bf_][(rA + f * 16) * 32 + kb]);            \
    _Pragma("unroll") for (int f = 0; f < WNF; ++f)                           \
      bvv[f] = *(const bf16x8*)(&Bs[bf_][(rB + f * 16) * 32 + kb]);           \
    _Pragma("unroll") for (int i = 0; i < 4; ++i)                             \
      _Pragma("unroll") for (int j = 0; j < WNF; ++j)                         \
        acc[i][j] = __builtin_amdgcn_mfma_f32_16x16x32_bf16(av[i], bvv[j],    \
                                                            acc[i][j], 0, 0, 0); \
  }

  const int nk = K / BK;
  STAGE(0, 0);
  if (nk > 1) STAGE(1, BK);
  int bc = 0, bs = 2;
  for (int k = 0; k + 1 < nk; ++k) {
    asm volatile("s_waitcnt vmcnt(%0)" :: "i"(LPW) : "memory");
    __builtin_amdgcn_s_barrier();
    if (k + 2 < nk) {
      STAGE(bs, (k + 2) * BK);
      bs = (bs == 2) ? 0 : bs + 1;
    }
    COMPUTE(bc);
    bc = (bc == 2) ? 0 : bc + 1;
  }
  asm volatile("s_waitcnt vmcnt(0)" ::: "memory");
  __builtin_amdgcn_s_barrier();
  COMPUTE(bc);
#undef STAGE
#undef COMPUTE

  void* Cout = sg.C;
  const float* bias = sg.bias;
  const float* e1 = sg.e1;
  const int em = m0 + wm + ((lane >> 4) << 2);
  const int en = n0 + wn + (lane & 15);

#define EPI_STORE(EPI_, OBF_)                                                 \
  { _Pragma("unroll") for (int fi = 0; fi < 4; ++fi) {                        \
      _Pragma("unroll") for (int fj = 0; fj < WNF; ++fj) {                    \
        const int gn = en + fj * 16;                                          \
        if (gn < N) {                                                         \
          _Pragma("unroll") for (int rr = 0; rr < 4; ++rr) {                  \
            const int gm = em + fi * 16 + rr;                                 \
            const size_t idx = (size_t)gm * N + gn;                           \
            const float y = acc[fi][fj][rr];                                  \
            float outv;                                                       \
            if (EPI_ == EPI_NONE) { outv = y; }                               \
            else if (EPI_ == EPI_TANH) { outv = tanhf(y); }                   \
            else if (EPI_ == EPI_SIG) { outv = sigm(y); }                     \
            else if (EPI_ == EPI_DECAY) {                                     \
              const float z = bias[gn] + y;                                   \
              const float w = -log1pf(expf(-z)) - 0.5f;                       \
              outv = expf(-expf(w));                                          \
            } else if (EPI_ == EPI_SIGB) { outv = sigm(bias[gn] + y); }       \
            else if (EPI_ == EPI_VMIX) {                                      \
              const float vr = ((float*)Cout)[idx];                           \
              outv = vr + (e1[idx] - vr) * sigm(bias[gn] + y);                \
            } else if (EPI_ == EPI_RELU2) {                                   \
              const float t = fmaxf(y, 0.f); outv = t * t;                    \
            } else { outv = ((float*)Cout)[idx] + y; }                        \
            if (OBF_) ((ushort_t*)Cout)[idx] = f2bf(outv);                    \
            else      ((float*)Cout)[idx] = outv;                             \
          }                                                                   \
        }                                                                     \
      } } }

  switch (sg.epi) {
    case EPI_NONE:  if (sg.obf) EPI_STORE(EPI_NONE, 1) else EPI_STORE(EPI_NONE, 0); break;
    case EPI_TANH:  EPI_STORE(EPI_TANH, 1); break;
    case EPI_SIG:   EPI_STORE(EPI_SIG, 1); break;
    case EPI_DECAY: EPI_STORE(EPI_DECAY, 0); break;
    case EPI_SIGB:  EPI_STORE(EPI_SIGB, 0); break;
    case EPI_VMIX:  EPI_STORE(EPI_VMIX, 0); break;
    case EPI_RELU2: EPI_STORE(EPI_RELU2, 1); break;
    case EPI_ADD:   EPI_STORE(EPI_ADD, 0); break;
  }
#undef EPI_STORE
}

// ---------------------------------------------------------------------------
// Weight prep: fp32 [L][K][N] -> bf16 [L][Npad][K] (transposed, zero-padded).
// ---------------------------------------------------------------------------
__global__ __launch_bounds__(256) void wprep_k(
    const float* __restrict__ in, ushort_t* __restrict__ out,
    int K, int N, int Npad)
{
  __shared__ float t[32][33];
  const int l = blockIdx.z;
  const int n0 = blockIdx.x * 32, k0 = blockIdx.y * 32;
  const int tx = threadIdx.x & 31, ty = threadIdx.x >> 5;
  const float* src = in + (size_t)l * K * N;
  ushort_t* dst = out + (size_t)l * Npad * K;
#pragma unroll
  for (int i = 0; i < 32; i += 8) {
    const int k = k0 + ty + i, n = n0 + tx;
    t[ty + i][tx] = (n < N) ? src[(size_t)k * N + n] : 0.f;
  }
  __syncthreads();
#pragma unroll
  for (int i = 0; i < 32; i += 8) {
    const int n = n0 + ty + i, k = k0 + tx;
    dst[(size_t)n * K + k] = f2bf(t[tx][ty + i]);
  }
}

// ---------------------------------------------------------------------------
// Wave-per-token elementwise. Block=256 (4 waves = 4 tokens); lane owns 8 ch.
// ---------------------------------------------------------------------------
__global__ __launch_bounds__(256) void lnmix6_k(
    const float* __restrict__ x, const float* __restrict__ w,
    const float* __restrict__ b, const float* __restrict__ xml,
    ushort_t* __restrict__ xr, ushort_t* __restrict__ xw,
    ushort_t* __restrict__ xk, ushort_t* __restrict__ xv,
    ushort_t* __restrict__ xa, ushort_t* __restrict__ xg)
{
  const int m = blockIdx.x * 4 + (threadIdx.x >> 6);
  const int lane = threadIdx.x & 63;
  const int c0 = lane << 3;
  const size_t idx = (size_t)m * CDIM + c0;
  const bool first = ((m & (TT - 1)) == 0);
  float v[8], p[8];
  *(float4*)&v[0] = *(const float4*)&x[idx];
  *(float4*)&v[4] = *(const float4*)&x[idx + 4];
  if (first) {
#pragma unroll
    for (int j = 0; j < 8; ++j) p[j] = 0.f;
  } else {
    *(float4*)&p[0] = *(const float4*)&x[idx - CDIM];
    *(float4*)&p[4] = *(const float4*)&x[idx - CDIM + 4];
  }
  float s = 0.f, sp = 0.f;
#pragma unroll
  for (int j = 0; j < 8; ++j) { s += v[j]; sp += p[j]; }
  s = wsum64(s); sp = wsum64(sp);
  const float mu = s * (1.f / 512.f), mup = sp * (1.f / 512.f);
  float q = 0.f, qp = 0.f;
#pragma unroll
  for (int j = 0; j < 8; ++j) {
    const float d1 = v[j] - mu, d2 = p[j] - mup;
    q += d1 * d1; qp += d2 * d2;
  }
  q = wsum64(q); qp = wsum64(qp);
  const float is = rsqrtf(q * (1.f / 512.f) + 1e-5f);
  const float isp = rsqrtf(qp * (1.f / 512.f) + 1e-5f);
  float wc[8], bc[8];
  *(float4*)&wc[0] = *(const float4*)&w[c0]; *(float4*)&wc[4] = *(const float4*)&w[c0 + 4];
  *(float4*)&bc[0] = *(const float4*)&b[c0]; *(float4*)&bc[4] = *(const float4*)&b[c0 + 4];
  float hv[8], dx[8];
#pragma unroll
  for (int j = 0; j < 8; ++j) {
    hv[j] = (v[j] - mu) * is * wc[j] + bc[j];
    const float hp = first ? 0.f : (p[j] - mup) * isp * wc[j] + bc[j];
    dx[j] = hp - hv[j];
  }
  ushort_t* outs[6] = {xr, xw, xk, xv, xa, xg};
#pragma unroll
  for (int o = 0; o < 6; ++o) {
    float mc[8];
    *(float4*)&mc[0] = *(const float4*)&xml[o * CDIM + c0];
    *(float4*)&mc[4] = *(const float4*)&xml[o * CDIM + c0 + 4];
    bf16x8 pk;
#pragma unroll
    for (int j = 0; j < 8; ++j) pk[j] = (short)f2bf(fmaf(dx[j], mc[j], hv[j]));
    *(bf16x8*)&outs[o][idx] = pk;
  }
}

__global__ __launch_bounds__(256) void lnmix1_k(
    const float* __restrict__ x, const float* __restrict__ w,
    const float* __restrict__ b, const float* __restrict__ coef,
    ushort_t* __restrict__ kf)
{
  const int m = blockIdx.x * 4 + (threadIdx.x >> 6);
  const int lane = threadIdx.x & 63;
  const int c0 = lane << 3;
  const size_t idx = (size_t)m * CDIM + c0;
  const bool first = ((m & (TT - 1)) == 0);
  float v[8], p[8];
  *(float4*)&v[0] = *(const float4*)&x[idx];
  *(float4*)&v[4] = *(const float4*)&x[idx + 4];
  if (first) {
#pragma unroll
    for (int j = 0; j < 8; ++j) p[j] = 0.f;
  } else {
    *(float4*)&p[0] = *(const float4*)&x[idx - CDIM];
    *(float4*)&p[4] = *(const float4*)&x[idx - CDIM + 4];
  }
  float s = 0.f, sp = 0.f;
#pragma unroll
  for (int j = 0; j < 8; ++j) { s += v[j]; sp += p[j]; }
  s = wsum64(s); sp = wsum64(sp);
  const float mu = s * (1.f / 512.f), mup = sp * (1.f / 512.f);
  float q = 0.f, qp = 0.f;
#pragma unroll
  for (int j = 0; j < 8; ++j) {
    const float d1 = v[j] - mu, d2 = p[j] - mup;
    q += d1 * d1; qp += d2 * d2;
  }
  q = wsum64(q); qp = wsum64(qp);
  const float is = rsqrtf(q * (1.f / 512.f) + 1e-5f);
  const float isp = rsqrtf(qp * (1.f / 512.f) + 1e-5f);
  bf16x8 pk;
#pragma unroll
  for (int j = 0; j < 8; ++j) {
    const float wc = w[c0 + j], bc = b[c0 + j];
    const float hv = (v[j] - mu) * is * wc + bc;
    const float hp = first ? 0.f : (p[j] - mup) * isp * wc + bc;
    pk[j] = (short)f2bf(fmaf(hp - hv, coef[c0 + j], hv));
  }
  *(bf16x8*)&kf[idx] = pk;
}

__global__ __launch_bounds__(256) void prep_k(
    float* __restrict__ k, const float* __restrict__ a,
    const float* __restrict__ kkp, const float* __restrict__ kap,
    float* __restrict__ aa, float* __restrict__ bb)
{
  const int m = blockIdx.x * 4 + (threadIdx.x >> 6);
  const int lane = threadIdx.x & 63;
  const int c0 = lane << 3;
  const size_t idx = (size_t)m * CDIM + c0;
  float kv[8], av[8], kp[8], ka[8];
  *(float4*)&kv[0] = *(const float4*)&k[idx];     *(float4*)&kv[4] = *(const float4*)&k[idx + 4];
  *(float4*)&av[0] = *(const float4*)&a[idx];     *(float4*)&av[4] = *(const float4*)&a[idx + 4];
  *(float4*)&kp[0] = *(const float4*)&kkp[c0];    *(float4*)&kp[4] = *(const float4*)&kkp[c0 + 4];
  *(float4*)&ka[0] = *(const float4*)&kap[c0];    *(float4*)&ka[4] = *(const float4*)&kap[c0 + 4];
  float kk[8], ss = 0.f;
#pragma unroll
  for (int j = 0; j < 8; ++j) { kk[j] = kv[j] * kp[j]; ss += kk[j] * kk[j]; }
  ss = gsum8(ss);
  const float rden = 1.f / fmaxf(sqrtf(ss), 1e-12f);
  float oaa[8], obb[8], okk[8];
#pragma unroll
  for (int j = 0; j < 8; ++j) {
    const float kkn = kk[j] * rden;
    oaa[j] = -kkn;
    obb[j] = kkn * av[j];
    okk[j] = kv[j] * (1.f + (av[j] - 1.f) * ka[j]);
  }
  *(float4*)&aa[idx] = *(float4*)&oaa[0]; *(float4*)&aa[idx + 4] = *(float4*)&oaa[4];
  *(float4*)&bb[idx] = *(float4*)&obb[0]; *(float4*)&bb[idx + 4] = *(float4*)&obb[4];
  *(float4*)&k[idx]  = *(float4*)&okk[0]; *(float4*)&k[idx + 4]  = *(float4*)&okk[4];
}

__global__ __launch_bounds__(256) void post_k(
    const float* __restrict__ o, const float* __restrict__ r,
    const float* __restrict__ k, const float* __restrict__ v,
    const float* __restrict__ g, const float* __restrict__ gw,
    const float* __restrict__ gb, const float* __restrict__ rkp,
    ushort_t* __restrict__ og)
{
  const int m = blockIdx.x * 4 + (threadIdx.x >> 6);
  const int lane = threadIdx.x & 63;
  const int c0 = lane << 3;
  const size_t idx = (size_t)m * CDIM + c0;
  float ov[8], rv[8], kv[8], vv[8], gv[8], rp[8];
  *(float4*)&ov[0] = *(const float4*)&o[idx];   *(float4*)&ov[4] = *(const float4*)&o[idx + 4];
  *(float4*)&rv[0] = *(const float4*)&r[idx];   *(float4*)&rv[4] = *(const float4*)&r[idx + 4];
  *(float4*)&kv[0] = *(const float4*)&k[idx];   *(float4*)&kv[4] = *(const float4*)&k[idx + 4];
  *(float4*)&vv[0] = *(const float4*)&v[idx];   *(float4*)&vv[4] = *(const float4*)&v[idx + 4];
  *(float4*)&gv[0] = *(const float4*)&g[idx];   *(float4*)&gv[4] = *(const float4*)&g[idx + 4];
  *(float4*)&rp[0] = *(const float4*)&rkp[c0];  *(float4*)&rp[4] = *(const float4*)&rkp[c0 + 4];
  float s = 0.f, dot = 0.f;
#pragma unroll
  for (int j = 0; j < 8; ++j) { s += ov[j]; dot += rv[j] * kv[j] * rp[j]; }
  s = gsum8(s); dot = gsum8(dot);
  const float mu = s * (1.f / 64.f);
  float q = 0.f;
#pragma unroll
  for (int j = 0; j < 8; ++j) { const float d = ov[j] - mu; q += d * d; }
  q = gsum8(q);
  const float is = rsqrtf(q * (1.f / 64.f) + 64e-5f);
  bf16x8 pk;
#pragma unroll
  for (int j = 0; j < 8; ++j) {
    const float gn = (ov[j] - mu) * is * gw[c0 + j] + gb[c0 + j];
    pk[j] = (short)f2bf((gn + dot * vv[j]) * gv[j]);
  }
  *(bf16x8*)&og[idx] = pk;
}

__global__ __launch_bounds__(512) void ln_final_k(
    const float* __restrict__ x, const float* __restrict__ w,
    const float* __restrict__ b, float* __restrict__ out)
{
  const int m = blockIdx.x, c = threadIdx.x;
  const size_t idx = (size_t)m * CDIM + c;
  const float v = x[idx];
  __shared__ float red[8], red2[8];
  float s = wsum64(v);
  if ((c & 63) == 0) red[c >> 6] = s;
  __syncthreads();
  float tot = 0.f;
#pragma unroll
  for (int u = 0; u < 8; ++u) tot += red[u];
  const float mu = tot * (1.f / 512.f);
  const float dv = v - mu;
  float s2 = wsum64(dv * dv);
  if ((c & 63) == 0) red2[c >> 6] = s2;
  __syncthreads();
  float vt = 0.f;
#pragma unroll
  for (int u = 0; u < 8; ++u) vt += red2[u];
  const float y = dv * rsqrtf(vt * (1.f / 512.f) + 1e-5f) * w[c] + b[c];
  const int bidx = m >> 10, t = m & 1023;
  const int p = t & 127, eb = bidx * 8 + (t >> 7);
  out[((size_t)eb * CDIM + c) * 128 + p] = y;
}

__global__ __launch_bounds__(512) void build_x_k(
    const float* __restrict__ img, const float* __restrict__ pos,
    float* __restrict__ x)
{
  const int m = blockIdx.x, c = threadIdx.x;
  const int bidx = m >> 10, t = m & 1023;
  const int p = t & 127, eb = bidx * 8 + (t >> 7);
  x[(size_t)m * CDIM + c] =
      img[((size_t)eb * CDIM + c) * 128 + p] + pos[(size_t)p * CDIM + c];
}

// ---------------------------------------------------------------------------
// Chunked RWKV7 scan. scan1: per chunk (LC=32), from S=0/P=I, per step emit
// o_local_t = Q_t r_t and y_t = P_t r_t; at end store P,Q for scan2.
// Thread (rg=tid>>4, cg=tid&15) owns 4x4 sub-tile; DPP row-reduce.
// ---------------------------------------------------------------------------
__global__ __launch_bounds__(256) void scan1_k(
    const float* __restrict__ r, const float* __restrict__ d,
    const float* __restrict__ k, const float* __restrict__ v,
    const float* __restrict__ aa, const float* __restrict__ bb,
    float* __restrict__ P, float* __restrict__ Q,
    float* __restrict__ Y, float* __restrict__ o)
{
  const int ch = blockIdx.x, bh = blockIdx.y;
  const int b = bh >> 3, hh = bh & 7;
  const int tid = threadIdx.x;
  const int rg = tid >> 4, cg = tid & 15;
  const int r0 = rg << 2, c0 = cg << 2;
  float S[16], Pr[16];
#pragma unroll
  for (int ri = 0; ri < 4; ++ri)
#pragma unroll
    for (int cj = 0; cj < 4; ++cj) {
      S[ri * 4 + cj] = 0.f;
      Pr[ri * 4 + cj] = (r0 + ri == c0 + cj) ? 1.f : 0.f;
    }

  __shared__ float sbuf[3][6 * TB * 64];   // 36 KB
  const size_t base = (size_t)b * TT * CDIM + (size_t)ch * LC * CDIM + hh * 64;
  const float* srcs[6] = {r, d, k, v, aa, bb};
  const int f0 = tid, f1 = tid + 256, f2 = tid + 512;
  const float* gp0 = srcs[f0 >> 7] + base + (size_t)((f0 >> 4) & 7) * CDIM + ((f0 & 15) << 2);
  const float* gp1 = srcs[f1 >> 7] + base + (size_t)((f1 >> 4) & 7) * CDIM + ((f1 & 15) << 2);
  const float* gp2 = srcs[f2 >> 7] + base + (size_t)((f2 >> 4) & 7) * CDIM + ((f2 & 15) << 2);
  const size_t pqbase = ((size_t)(bh * NCH + ch)) * 4096;
  const size_t ybase0 = ((size_t)(bh * NCH + ch)) * (LC * 64);

#define STAGE1(bf_, goff_)                          \
  {                                                 \
    glds16(gp0 + (goff_), &sbuf[bf_][f0 << 2]);     \
    glds16(gp1 + (goff_), &sbuf[bf_][f1 << 2]);     \
    glds16(gp2 + (goff_), &sbuf[bf_][f2 << 2]);     \
  }

#define CGRP1(bf_, g_)                                                          \
  {                                                                             \
    const float* sb0 = sbuf[bf_];                                               \
    const size_t obase = base + (size_t)(g_) * TB * CDIM;                       \
    const size_t ybase = ybase0 + (size_t)(g_) * TB * 64;                       \
    _Pragma("unroll") for (int tt = 0; tt < TB; ++tt) {                         \
      const float* sr  = sb0 + 0 * TB * 64 + tt * 64;                           \
      const float* sd  = sb0 + 1 * TB * 64 + tt * 64;                           \
      const float* sk  = sb0 + 2 * TB * 64 + tt * 64;                           \
      const float* sv  = sb0 + 3 * TB * 64 + tt * 64;                           \
      const float* sa  = sb0 + 4 * TB * 64 + tt * 64;                           \
      const float* sbv = sb0 + 5 * TB * 64 + tt * 64;                           \
      const float4 a4 = *(const float4*)(sa + c0);                              \
      const float4 d4 = *(const float4*)(sd + c0);                              \
      const float4 k4 = *(const float4*)(sk + c0);                              \
      const float4 b4 = *(const float4*)(sbv + c0);                             \
      const float4 r4 = *(const float4*)(sr + c0);                              \
      const float4 v4 = *(const float4*)(sv + r0);                              \
      const float dd[4] = {d4.x, d4.y, d4.z, d4.w};                             \
      const float ak[4] = {a4.x, a4.y, a4.z, a4.w};                             \
      const float kc[4] = {k4.x, k4.y, k4.z, k4.w};                             \
      const float bc2[4] = {b4.x, b4.y, b4.z, b4.w};                            \
      const float rr[4] = {r4.x, r4.y, r4.z, r4.w};                             \
      const float vr[4] = {v4.x, v4.y, v4.z, v4.w};                             \
      float ps[4], pp[4];                                                       \
      _Pragma("unroll") for (int ri = 0; ri < 4; ++ri) {                        \
        ps[ri] = fmaf(S[ri*4+0], ak[0], fmaf(S[ri*4+1], ak[1],                  \
                 fmaf(S[ri*4+2], ak[2], S[ri*4+3] * ak[3])));                   \
        pp[ri] = fmaf(Pr[ri*4+0], ak[0], fmaf(Pr[ri*4+1], ak[1],                \
                 fmaf(Pr[ri*4+2], ak[2], Pr[ri*4+3] * ak[3])));                 \
      }                                                                         \
      _Pragma("unroll") for (int ri = 0; ri < 4; ++ri) {                        \
        ps[ri] = rowsum16(ps[ri]);                                              \
        pp[ri] = rowsum16(pp[ri]);                                              \
      }                                                                         \
      float yv[4], ol[4];                                                       \
      _Pragma("unroll") for (int ri = 0; ri < 4; ++ri) {                        \
        float yacc = 0.f, oacc = 0.f;                                           \
        _Pragma("unroll") for (int cj = 0; cj < 4; ++cj) {                      \
          const float sn = fmaf(S[ri*4+cj], dd[cj],                             \
                           fmaf(ps[ri], bc2[cj], vr[ri] * kc[cj]));             \
          const float pn = fmaf(Pr[ri*4+cj], dd[cj], pp[ri] * bc2[cj]);         \
          S[ri*4+cj] = sn;                                                      \
          Pr[ri*4+cj] = pn;                                                     \
          oacc = fmaf(sn, rr[cj], oacc);                                        \
          yacc = fmaf(pn, rr[cj], yacc);                                        \
        }                                                                       \
        ol[ri] = oacc; yv[ri] = yacc;                                           \
      }                                                                         \
      _Pragma("unroll") for (int ri = 0; ri < 4; ++ri) {                        \
        ol[ri] = rowsum16(ol[ri]);                                              \
        yv[ri] = rowsum16(yv[ri]);                                              \
      }                                                                         \
      if (cg == 0) {                                                            \
        *(float4*)&o[obase + (size_t)tt * CDIM + r0] =                          \
            make_float4(ol[0], ol[1], ol[2], ol[3]);                            \
        *(float4*)&Y[ybase + (size_t)tt * 64 + r0] =                            \
            make_float4(yv[0], yv[1], yv[2], yv[3]);                            \
      }                                                                         \
    }                                                                           \
  }

  constexpr int NG = LC / TB;   // 4
  STAGE1(0, 0);
  STAGE1(1, (size_t)TB * CDIM);
  int bc = 0, bs = 2;
  for (int g = 0; g + 1 < NG; ++g) {
    asm volatile("s_waitcnt vmcnt(3)" ::: "memory");
    __builtin_amdgcn_s_barrier();
    if (g + 2 < NG) {
      STAGE1(bs, (size_t)(g + 2) * TB * CDIM);
      bs = (bs == 2) ? 0 : bs + 1;
    }
    CGRP1(bc, g);
    bc = (bc == 2) ? 0 : bc + 1;
  }
  asm volatile("s_waitcnt vmcnt(0)" ::: "memory");
  __builtin_amdgcn_s_barrier();
  CGRP1(bc, NG - 1);
#undef STAGE1
#undef CGRP1

  const size_t ob = pqbase + (size_t)r0 * 64 + c0;
#pragma unroll
  for (int ri = 0; ri < 4; ++ri) {
    *(float4*)&Q[ob + ri * 64] = make_float4(S[ri*4+0], S[ri*4+1], S[ri*4+2], S[ri*4+3]);
    *(float4*)&P[ob + ri * 64] = make_float4(Pr[ri*4+0], Pr[ri*4+1], Pr[ri*4+2], Pr[ri*4+3]);
  }
}

// scan2: sequential chunk composition, coalesced, register-prefetched.
// Sst aliases Q: Q[c] is read into registers BEFORE Sst[c] is stored.
__global__ __launch_bounds__(512) void scan2_k(
    const float* __restrict__ P, const float* __restrict__ Q,
    float* __restrict__ Sst)
{
  const int tid = threadIdx.x;
  const int f0 = tid << 2;
  const int r0 = tid >> 4;
  const int c0 = (tid & 15) << 2;
  __shared__ float sP[4096];
  __shared__ float sS[4096];
  float4 S0 = {0.f, 0.f, 0.f, 0.f}, S1 = {0.f, 0.f, 0.f, 0.f};
  const size_t cbase = (size_t)blockIdx.x * NCH * 4096;
  float4 pf0 = *(const float4*)&P[cbase + f0];
  float4 pf1 = *(const float4*)&P[cbase + f0 + 2048];

  for (int c = 0; c < NCH; ++c) {
    const size_t cb = cbase + (size_t)c * 4096;
    const float4 q0 = *(const float4*)&Q[cb + f0];          // read Q first
    const float4 q1 = *(const float4*)&Q[cb + f0 + 2048];
    *(float4*)&Sst[cb + f0] = S0;                           // then overwrite
    *(float4*)&Sst[cb + f0 + 2048] = S1;
    __syncthreads();
    *(float4*)&sP[f0] = pf0;  *(float4*)&sP[f0 + 2048] = pf1;
    *(float4*)&sS[f0] = S0;   *(float4*)&sS[f0 + 2048] = S1;
    __syncthreads();
    if (c + 1 < NCH) {
      pf0 = *(const float4*)&P[cb + 4096 + f0];
      pf1 = *(const float4*)&P[cb + 4096 + f0 + 2048];
    }

    float a00 = 0.f, a01 = 0.f, a02 = 0.f, a03 = 0.f;
    float a10 = 0.f, a11 = 0.f, a12 = 0.f, a13 = 0.f;
    const float* sS0 = &sS[r0 * 64];
    const float* sS1 = &sS[(r0 + 32) * 64];
#pragma unroll
    for (int mm = 0; mm < 64; ++mm) {
      const float4 p4 = *(const float4*)&sP[mm * 64 + c0];
      const float u0 = sS0[mm], u1 = sS1[mm];
      a00 = fmaf(u0, p4.x, a00); a01 = fmaf(u0, p4.y, a01);
      a02 = fmaf(u0, p4.z, a02); a03 = fmaf(u0, p4.w, a03);
      a10 = fmaf(u1, p4.x, a10); a11 = fmaf(u1, p4.y, a11);
      a12 = fmaf(u1, p4.z, a12); a13 = fmaf(u1, p4.w, a13);
    }
    S0.x = a00 + q0.x; S0.y = a01 + q0.y; S0.z = a02 + q0.z; S0.w = a03 + q0.w;
    S1.x = a10 + q1.x; S1.y = a11 + q1.y; S1.z = a12 + q1.z; S1.w = a13 + q1.w;
  }
}

// corr: o[t][i] += sum_j Sst[i][j] * Y[t][j]  (one LC=32 chunk per block).
__global__ __launch_bounds__(256) void corr_k(
    const float* __restrict__ Sst, const float* __restrict__ Y,
    float* __restrict__ o)
{
  const int ch = blockIdx.x, bh = blockIdx.y;
  const int b = bh >> 3, hh = bh & 7;
  const int tid = threadIdx.x;
  __shared__ float ST[64][68];   // ST[j][i] = Sst[i][j]
  __shared__ float Yl[LC][68];   // Yl[t][j]
  const size_t cb = ((size_t)(bh * NCH + ch)) * 4096;
  const size_t yb = ((size_t)(bh * NCH + ch)) * (LC * 64);
#pragma unroll
  for (int u = 0; u < 16; ++u) {
    const int idx = tid + 256 * u;
    ST[idx & 63][idx >> 6] = Sst[cb + idx];
  }
#pragma unroll
  for (int u = 0; u < 2; ++u) {
    const int fi = tid + 256 * u;              // float4 index 0..511
    *(float4*)&Yl[fi >> 4][(fi & 15) << 2] = *(const float4*)&Y[yb + (size_t)fi * 4];
  }
  __syncthreads();
  const int t = tid >> 3, q = tid & 7, i0 = q << 3;
  f32x4 acc[2];
#pragma unroll
  for (int u = 0; u < 2; ++u) acc[u] = (f32x4){0.f, 0.f, 0.f, 0.f};
  const float* yrow = &Yl[t][0];
#pragma unroll 4
  for (int j = 0; j < 64; ++j) {
    const float yv = yrow[j];
#pragma unroll
    for (int u = 0; u < 2; ++u) {
      const f32x4 s4 = *(const f32x4*)&ST[j][i0 + 4 * u];
      acc[u] = {fmaf(yv, s4[0], acc[u][0]), fmaf(yv, s4[1], acc[u][1]),
                fmaf(yv, s4[2], acc[u][2]), fmaf(yv, s4[3], acc[u][3])};
    }
  }
  const size_t obase = (size_t)b * TT * CDIM + (size_t)ch * LC * CDIM + hh * 64 +
                       (size_t)t * CDIM + i0;
#pragma unroll
  for (int u = 0; u < 2; ++u) {
    float4 cur = *(const float4*)&o[obase + 4 * u];
    cur.x += acc[u][0]; cur.y += acc[u][1]; cur.z += acc[u][2]; cur.w += acc[u][3];
    *(float4*)&o[obase + 4 * u] = cur;
  }
}

// ---------------------------------------------------------------------------
extern "C" void kernel_launch(void* const* d_in, const int* in_sizes, int n_in,
                              void* d_out, int out_size, void* d_ws, size_t ws_size,
                              hipStream_t stream) {
  (void)in_sizes; (void)n_in; (void)out_size; (void)ws_size;
  const float* img  = (const float*)d_in[0];
  const float* pos  = (const float*)d_in[1];
  const float* xm   = (const float*)d_in[2];
  const float* w0   = (const float*)d_in[3];
  const float* w1   = (const float*)d_in[4];
  const float* w2   = (const float*)d_in[5];
  const float* a0   = (const float*)d_in[6];
  const float* a1   = (const float*)d_in[7];
  const float* a2   = (const float*)d_in[8];
  const float* v0   = (const float*)d_in[9];
  const float* v1   = (const float*)d_in[10];
  const float* v2   = (const float*)d_in[11];
  const float* g1   = (const float*)d_in[12];
  const float* g2   = (const float*)d_in[13];
  const float* kkp  = (const float*)d_in[14];
  const float* kap  = (const float*)d_in[15];
  const float* rkp  = (const float*)d_in[16];
  const float* Wr   = (const float*)d_in[17];
  const float* Wk   = (const float*)d_in[18];
  const float* Wv   = (const float*)d_in[19];
  const float* Wo   = (const float*)d_in[20];
  const float* lnxw = (const float*)d_in[21];
  const float* lnxb = (const float*)d_in[22];
  const float* ln1w = (const float*)d_in[23];
  const float* ln1b = (const float*)d_in[24];
  const float* ln2w = (const float*)d_in[25];
  const float* ln2b = (const float*)d_in[26];
  const float* fxk  = (const float*)d_in[27];
  const float* Wkey = (const float*)d_in[28];
  const float* Wval = (const float*)d_in[29];
  const float* lnfw = (const float*)d_in[30];
  const float* lnfb = (const float*)d_in[31];

  float* ws = (float*)d_ws;
  const size_t SZ = (size_t)NTOK * CDIM;   // 2M elements
  float* x   = ws + 0 * SZ;
  float* r_  = ws + 2 * SZ;
  float* dec = ws + 3 * SZ;
  float* k_  = ws + 4 * SZ;
  float* v_  = ws + 5 * SZ;
  float* vf  = ws + 6 * SZ;
  float* a_  = ws + 7 * SZ;
  float* g_  = ws + 8 * SZ;
  float* aa  = ws + 9 * SZ;
  float* bb  = ws + 10 * SZ;
  float* o_  = ws + 11 * SZ;
  float* mixf = ws + 12 * SZ;
  ushort_t* xr = (ushort_t*)mixf;
  ushort_t* xw = xr + SZ;
  ushort_t* xk = xr + 2 * SZ;
  ushort_t* xv = xr + 3 * SZ;
  ushort_t* xa = xr + 4 * SZ;
  ushort_t* xg = xr + 5 * SZ;
  // scan scratch (dead regions during scan window):
  float* Pbuf = ws + 12 * SZ;   // 16 MB (slots 12-13; xr..xk dead by scan)
  float* Qbuf = ws + 14 * SZ;   // 16 MB (slots 14-15; xa,xg,tmpb dead by scan)
  float* Sst  = Qbuf;           // composed in place (Q[c] read before write)
  float* Ybuf = ws + 16 * SZ;   // 8 MB (slot 16; tfb written after corr)
  ushort_t* tmpb = (ushort_t*)(ws + 15 * SZ);            // 4096 x 288 bf16
  ushort_t* t0b = tmpb;
  ushort_t* t1b = tmpb + (size_t)NTOK * 64;
  ushort_t* t2b = tmpb + (size_t)NTOK * 128;
  ushort_t* t3b = tmpb + (size_t)NTOK * 160;
  ushort_t* tfb  = (ushort_t*)(ws + 15 * SZ + SZ / 2);   // 4096 x 2048 bf16
  ushort_t* ogb  = (ushort_t*)(ws + 17 * SZ + SZ / 2);   // 4096 x 512 bf16
  ushort_t* wb   = (ushort_t*)(ws + 18 * SZ);            // bf16 weights

  const size_t oWr  = 0;
  const size_t oWk  = oWr  + (size_t)8 * 512 * 512;
  const size_t oWv  = oWk  + (size_t)8 * 512 * 512;
  const size_t oWo  = oWv  + (size_t)8 * 512 * 512;
  const size_t oW1  = oWo  + (size_t)8 * 512 * 512;
  const size_t oW2  = oW1  + (size_t)8 * 128 * 512;
  const size_t oA1  = oW2  + (size_t)8 * 512 * 64;
  const size_t oA2  = oA1  + (size_t)8 * 128 * 512;
  const size_t oV1  = oA2  + (size_t)8 * 512 * 64;
  const size_t oV2  = oV1  + (size_t)8 * 128 * 512;
  const size_t oG1  = oV2  + (size_t)8 * 512 * 32;
  const size_t oG2  = oG1  + (size_t)8 * 128 * 512;
  const size_t oKey = oG2  + (size_t)8 * 512 * 128;
  const size_t oVal = oKey + (size_t)8 * 2048 * 512;

#define WPREP(src, dst, K_, N_, NP_) \
  wprep_k<<<dim3((NP_) / 32, (K_) / 32, 8), 256, 0, stream>>>(src, dst, K_, N_, NP_)
  WPREP(Wr,   wb + oWr,  512, 512, 512);
  WPREP(Wk,   wb + oWk,  512, 512, 512);
  WPREP(Wv,   wb + oWv,  512, 512, 512);
  WPREP(Wo,   wb + oWo,  512, 512, 512);
  WPREP(w1,   wb + oW1,  512, 64,  128);
  WPREP(w2,   wb + oW2,  64,  512, 512);
  WPREP(a1,   wb + oA1,  512, 64,  128);
  WPREP(a2,   wb + oA2,  64,  512, 512);
  WPREP(v1,   wb + oV1,  512, 32,  128);
  WPREP(v2,   wb + oV2,  32,  512, 512);
  WPREP(g1,   wb + oG1,  512, 128, 128);
  WPREP(g2,   wb + oG2,  128, 512, 512);
  WPREP(Wkey, wb + oKey, 512, 2048, 2048);
  WPREP(Wval, wb + oVal, 2048, 512, 512);
#undef WPREP

  build_x_k<<<NTOK, 512, 0, stream>>>(img, pos, x);

  for (int l = 0; l < 8; ++l) {
    const size_t lc = (size_t)l * CDIM;
    const float* xml = xm + (size_t)l * 6 * CDIM;
    const ushort_t* bWr = wb + oWr + (size_t)l * 512 * 512;
    const ushort_t* bWk = wb + oWk + (size_t)l * 512 * 512;
    const ushort_t* bWv = wb + oWv + (size_t)l * 512 * 512;
    const ushort_t* bWo = wb + oWo + (size_t)l * 512 * 512;
    const ushort_t* bW1 = wb + oW1 + (size_t)l * 128 * 512;
    const ushort_t* bW2 = wb + oW2 + (size_t)l * 512 * 64;
    const ushort_t* bA1 = wb + oA1 + (size_t)l * 128 * 512;
    const ushort_t* bA2 = wb + oA2 + (size_t)l * 512 * 64;
    const ushort_t* bV1 = wb + oV1 + (size_t)l * 128 * 512;
    const ushort_t* bV2 = wb + oV2 + (size_t)l * 512 * 32;
    const ushort_t* bG1 = wb + oG1 + (size_t)l * 128 * 512;
    const ushort_t* bG2 = wb + oG2 + (size_t)l * 512 * 128;
    const ushort_t* bKy = wb + oKey + (size_t)l * 2048 * 512;
    const ushort_t* bVl = wb + oVal + (size_t)l * 512 * 2048;
    float* vdst = (l == 0) ? vf : v_;

    // ---- time mix ----
    lnmix6_k<<<NTOK / 4, 256, 0, stream>>>(x, ln1w + lc, ln1b + lc, xml,
                                           xr, xw, xk, xv, xa, xg);
    Segs4 qkv;
    qkv.s[0] = {xr, bWr, r_,   0, 0, 512, 512, EPI_NONE, 0};
    qkv.s[1] = {xk, bWk, k_,   0, 0, 512, 512, EPI_NONE, 0};
    qkv.s[2] = {xv, bWv, vdst, 0, 0, 512, 512, EPI_NONE, 0};
    qkv.s[3] = {0, 0, 0, 0, 0, 0, 0, -1, 0};
    ggemm_k<64><<<dim3(NTOK / BM, 8, 3), 256, 0, stream>>>(qkv);

    Segs4 dn;
    dn.s[0] = {xw, bW1, t0b, 0, 0, 64,  512, EPI_TANH, 1};
    dn.s[1] = {xa, bA1, t1b, 0, 0, 64,  512, EPI_NONE, 1};
    dn.s[2] = {xv, bV1, t2b, 0, 0, 32,  512, EPI_NONE, 1};
    dn.s[3] = {xg, bG1, t3b, 0, 0, 128, 512, EPI_SIG,  1};
    ggemm_k<64><<<dim3(NTOK / BM, 2, 4), 256, 0, stream>>>(dn);

    Segs4 up;
    up.s[0] = {t0b, bW2, dec, w0 + lc, 0,  512, 64,  EPI_DECAY, 0};
    up.s[1] = {t1b, bA2, a_,  a0 + lc, 0,  512, 64,  EPI_SIGB,  0};
    up.s[2] = {t2b, bV2, v_,  v0 + lc, vf, 512, 32,  (l > 0) ? EPI_VMIX : -1, 0};
    up.s[3] = {t3b, bG2, g_,  0, 0,        512, 128, EPI_NONE,  0};
    ggemm_k<64><<<dim3(NTOK / BM, 8, 4), 256, 0, stream>>>(up);

    const float* vptr = (l == 0) ? vf : v_;
    prep_k<<<NTOK / 4, 256, 0, stream>>>(k_, a_, kkp + lc, kap + lc, aa, bb);
    scan1_k<<<dim3(NCH, 32), 256, 0, stream>>>(r_, dec, k_, vptr, aa, bb,
                                               Pbuf, Qbuf, Ybuf, o_);
    scan2_k<<<32, 512, 0, stream>>>(Pbuf, Qbuf, Sst);
    corr_k<<<dim3(NCH, 32), 256, 0, stream>>>(Sst, Ybuf, o_);
    post_k<<<NTOK / 4, 256, 0, stream>>>(o_, r_, k_, vptr, g_, lnxw + lc, lnxb + lc,
                                         rkp + lc, ogb);
    Segs4 wo;
    wo.s[0] = {ogb, bWo, x, 0, 0, 512, 512, EPI_ADD, 0};
    wo.s[1] = wo.s[2] = wo.s[3] = {0, 0, 0, 0, 0, 0, 0, -1, 0};
    ggemm_k<64><<<dim3(NTOK / BM, 8, 1), 256, 0, stream>>>(wo);

    // ---- channel mix ----
    lnmix1_k<<<NTOK / 4, 256, 0, stream>>>(x, ln2w + lc, ln2b + lc, fxk + lc, xr);
    Segs4 f1;
    f1.s[0] = {xr, bKy, tfb, 0, 0, 2048, 512, EPI_RELU2, 1};
    f1.s[1] = f1.s[2] = f1.s[3] = {0, 0, 0, 0, 0, 0, 0, -1, 0};
    ggemm_k<64><<<dim3(NTOK / BM, 32, 1), 256, 0, stream>>>(f1);
    Segs4 f2;
    f2.s[0] = {tfb, bVl, x, 0, 0, 512, 2048, EPI_ADD, 0};
    f2.s[1] = f2.s[2] = f2.s[3] = {0, 0, 0, 0, 0, 0, 0, -1, 0};
    ggemm_k<64><<<dim3(NTOK / BM, 8, 1), 256, 0, stream>>>(f2);
  }

  ln_final_k<<<NTOK, 512, 0, stream>>>(x, lnfw, lnfb, (float*)d_out);
}

// Round 12
// 2208.707 us; speedup vs baseline: 1.1148x; 1.1148x over previous
//
#include <hip/hip_runtime.h>
#include <hip/hip_bf16.h>
#include <math.h>

// ---------------------------------------------------------------------------
// RWKV7 vision block. Pipelined bf16 MFMA GEMMs (3-buf counted-vmcnt) +
// chunked parallel scan (LC=64): scan1 emits P,Q,y=P*r,o_local; scan2
// (P and Q register-prefetched) composes chunk states; corr adds S_start @ y.
// B=4, T=1024, C=512, H=8, N=64, L=8.
// ---------------------------------------------------------------------------

#define NTOK 4096
#define CDIM 512
#define TT   1024
#define LC   64
#define NCH  16
#define TB   8      // scan time-steps per LDS stage group

#define BM 128
#define BK 32

enum { EPI_NONE=0, EPI_TANH, EPI_SIG, EPI_DECAY, EPI_SIGB, EPI_VMIX, EPI_RELU2, EPI_ADD };

typedef short bf16x8 __attribute__((ext_vector_type(8)));
typedef float f32x4 __attribute__((ext_vector_type(4)));
typedef unsigned short ushort_t;

__device__ __forceinline__ float wsum64(float v) {
#pragma unroll
  for (int s = 1; s < 64; s <<= 1) v += __shfl_xor(v, s);
  return v;
}
__device__ __forceinline__ float gsum8(float v) {
  v += __shfl_xor(v, 1); v += __shfl_xor(v, 2); v += __shfl_xor(v, 4);
  return v;
}
// Sum over the 16 lanes of a DPP row (all lanes receive the total).
__device__ __forceinline__ float rowsum16(float x) {
  int t;
  t = __builtin_amdgcn_mov_dpp(__builtin_bit_cast(int, x), 0x128, 0xF, 0xF, true); // row_ror:8
  x += __builtin_bit_cast(float, t);
  t = __builtin_amdgcn_mov_dpp(__builtin_bit_cast(int, x), 0x124, 0xF, 0xF, true); // row_ror:4
  x += __builtin_bit_cast(float, t);
  t = __builtin_amdgcn_mov_dpp(__builtin_bit_cast(int, x), 0x122, 0xF, 0xF, true); // row_ror:2
  x += __builtin_bit_cast(float, t);
  t = __builtin_amdgcn_mov_dpp(__builtin_bit_cast(int, x), 0x121, 0xF, 0xF, true); // row_ror:1
  x += __builtin_bit_cast(float, t);
  return x;
}
__device__ __forceinline__ float sigm(float z) { return 1.f / (1.f + expf(-z)); }
__device__ __forceinline__ ushort_t f2bf(float x) {
  return __builtin_bit_cast(unsigned short, __float2bfloat16(x));
}
__device__ __forceinline__ void glds16(const void* g, void* l) {
  __builtin_amdgcn_global_load_lds(
      (const __attribute__((address_space(1))) void*)g,
      (__attribute__((address_space(3))) void*)l, 16, 0, 0);
}

// ---------------------------------------------------------------------------
// Grouped bf16 MFMA GEMM:  C[M,N] = epi(A[M,K] @ B[Npad,K]^T), per-z segment.
// ---------------------------------------------------------------------------
struct Seg {
  const ushort_t* A; const ushort_t* B; void* C;
  const float* bias; const float* e1;
  int N; int K; int epi; int obf;
};
struct Segs4 { Seg s[4]; };

template<int BNt>
__global__ __launch_bounds__(256) void ggemm_k(Segs4 segs) {
  const Seg sg = segs.s[blockIdx.z];
  if (sg.epi < 0) return;
  constexpr int NCHK = 8 + BNt / 16;
  constexpr int LPW  = NCHK / 4;
  constexpr int WNF  = BNt / 32;
  __shared__ ushort_t As[3][BM * BK];
  __shared__ ushort_t Bs[3][BNt * BK];
  const ushort_t* __restrict__ A = sg.A;
  const ushort_t* __restrict__ B = sg.B;
  const int N = sg.N, K = sg.K;
  const int tid = threadIdx.x;
  const int wave = tid >> 6, lane = tid & 63;
  const int m0 = blockIdx.x * BM, n0 = blockIdx.y * BNt;
  const int wm = (wave >> 1) << 6, wn = (wave & 1) * (BNt / 2);

  f32x4 zero = {0.f, 0.f, 0.f, 0.f};
  f32x4 acc[4][WNF];
#pragma unroll
  for (int i = 0; i < 4; ++i)
#pragma unroll
    for (int j = 0; j < WNF; ++j) acc[i][j] = zero;

  const int crow = lane >> 2;
  const int soff = (((lane & 3) ^ (crow & 3)) << 3);
  const ushort_t* gptr[LPW];
  ushort_t* lbase[LPW];
  int lstr[LPW];
#pragma unroll
  for (int i = 0; i < LPW; ++i) {
    const int c = wave + 4 * i;
    if (c < 8) {
      gptr[i] = A + (size_t)(m0 + c * 16 + crow) * K + soff;
      lbase[i] = &As[0][c * 512 + lane * 8];
      lstr[i] = BM * BK;
    } else {
      gptr[i] = B + (size_t)(n0 + (c - 8) * 16 + crow) * K + soff;
      lbase[i] = &Bs[0][(c - 8) * 512 + lane * 8];
      lstr[i] = BNt * BK;
    }
  }

#define STAGE(bf_, k0_)                                        \
  { _Pragma("unroll") for (int i = 0; i < LPW; ++i)            \
      glds16(gptr[i] + (k0_), lbase[i] + (bf_) * lstr[i]); }

  const int rA = wm + (lane & 15);
  const int rB = wn + (lane & 15);
  const int kb = (((lane >> 4) ^ (lane & 3)) << 3);

#define COMPUTE(bf_)                                                          \
  {                                                                           \
    bf16x8 av[4], bvv[WNF];                                                   \
    _Pragma("unroll") for (int f = 0; f < 4; ++f)                             \
      av[f] = *(const bf16x8*)(&As[bf_][(rA + f * 16) * 32 + kb]);            \
    _Pragma("unroll") for (int f = 0; f < WNF; ++f)                           \
      bvv[f] = *(const bf16x8*)(&Bs[bf_][(rB + f * 16) * 32 + kb]);           \
    _Pragma("unroll") for (int i = 0; i < 4; ++i)                             \
      _Pragma("unroll") for (int j = 0; j < WNF; ++j)                         \
        acc[i][j] = __builtin_amdgcn_mfma_f32_16x16x32_bf16(av[i], bvv[j],    \
                                                            acc[i][j], 0, 0, 0); \
  }

  const int nk = K / BK;
  STAGE(0, 0);
  if (nk > 1) STAGE(1, BK);
  int bc = 0, bs = 2;
  for (int k = 0; k + 1 < nk; ++k) {
    asm volatile("s_waitcnt vmcnt(%0)" :: "i"(LPW) : "memory");
    __builtin_amdgcn_s_barrier();
    if (k + 2 < nk) {
      STAGE(bs, (k + 2) * BK);
      bs = (bs == 2) ? 0 : bs + 1;
    }
    COMPUTE(bc);
    bc = (bc == 2) ? 0 : bc + 1;
  }
  asm volatile("s_waitcnt vmcnt(0)" ::: "memory");
  __builtin_amdgcn_s_barrier();
  COMPUTE(bc);
#undef STAGE
#undef COMPUTE

  void* Cout = sg.C;
  const float* bias = sg.bias;
  const float* e1 = sg.e1;
  const int em = m0 + wm + ((lane >> 4) << 2);
  const int en = n0 + wn + (lane & 15);

#define EPI_STORE(EPI_, OBF_)                                                 \
  { _Pragma("unroll") for (int fi = 0; fi < 4; ++fi) {                        \
      _Pragma("unroll") for (int fj = 0; fj < WNF; ++fj) {                    \
        const int gn = en + fj * 16;                                          \
        if (gn < N) {                                                         \
          _Pragma("unroll") for (int rr = 0; rr < 4; ++rr) {                  \
            const int gm = em + fi * 16 + rr;                                 \
            const size_t idx = (size_t)gm * N + gn;                           \
            const float y = acc[fi][fj][rr];                                  \
            float outv;                                                       \
            if (EPI_ == EPI_NONE) { outv = y; }                               \
            else if (EPI_ == EPI_TANH) { outv = tanhf(y); }                   \
            else if (EPI_ == EPI_SIG) { outv = sigm(y); }                     \
            else if (EPI_ == EPI_DECAY) {                                     \
              const float z = bias[gn] + y;                                   \
              const float w = -log1pf(expf(-z)) - 0.5f;                       \
              outv = expf(-expf(w));                                          \
            } else if (EPI_ == EPI_SIGB) { outv = sigm(bias[gn] + y); }       \
            else if (EPI_ == EPI_VMIX) {                                      \
              const float vr = ((float*)Cout)[idx];                           \
              outv = vr + (e1[idx] - vr) * sigm(bias[gn] + y);                \
            } else if (EPI_ == EPI_RELU2) {                                   \
              const float t = fmaxf(y, 0.f); outv = t * t;                    \
            } else { outv = ((float*)Cout)[idx] + y; }                        \
            if (OBF_) ((ushort_t*)Cout)[idx] = f2bf(outv);                    \
            else      ((float*)Cout)[idx] = outv;                             \
          }                                                                   \
        }                                                                     \
      } } }

  switch (sg.epi) {
    case EPI_NONE:  if (sg.obf) EPI_STORE(EPI_NONE, 1) else EPI_STORE(EPI_NONE, 0); break;
    case EPI_TANH:  EPI_STORE(EPI_TANH, 1); break;
    case EPI_SIG:   EPI_STORE(EPI_SIG, 1); break;
    case EPI_DECAY: EPI_STORE(EPI_DECAY, 0); break;
    case EPI_SIGB:  EPI_STORE(EPI_SIGB, 0); break;
    case EPI_VMIX:  EPI_STORE(EPI_VMIX, 0); break;
    case EPI_RELU2: EPI_STORE(EPI_RELU2, 1); break;
    case EPI_ADD:   EPI_STORE(EPI_ADD, 0); break;
  }
#undef EPI_STORE
}

// ---------------------------------------------------------------------------
// Weight prep: fp32 [L][K][N] -> bf16 [L][Npad][K] (transposed, zero-padded).
// ---------------------------------------------------------------------------
__global__ __launch_bounds__(256) void wprep_k(
    const float* __restrict__ in, ushort_t* __restrict__ out,
    int K, int N, int Npad)
{
  __shared__ float t[32][33];
  const int l = blockIdx.z;
  const int n0 = blockIdx.x * 32, k0 = blockIdx.y * 32;
  const int tx = threadIdx.x & 31, ty = threadIdx.x >> 5;
  const float* src = in + (size_t)l * K * N;
  ushort_t* dst = out + (size_t)l * Npad * K;
#pragma unroll
  for (int i = 0; i < 32; i += 8) {
    const int k = k0 + ty + i, n = n0 + tx;
    t[ty + i][tx] = (n < N) ? src[(size_t)k * N + n] : 0.f;
  }
  __syncthreads();
#pragma unroll
  for (int i = 0; i < 32; i += 8) {
    const int n = n0 + ty + i, k = k0 + tx;
    dst[(size_t)n * K + k] = f2bf(t[tx][ty + i]);
  }
}

// ---------------------------------------------------------------------------
// Wave-per-token elementwise. Block=256 (4 waves = 4 tokens); lane owns 8 ch.
// ---------------------------------------------------------------------------
__global__ __launch_bounds__(256) void lnmix6_k(
    const float* __restrict__ x, const float* __restrict__ w,
    const float* __restrict__ b, const float* __restrict__ xml,
    ushort_t* __restrict__ xr, ushort_t* __restrict__ xw,
    ushort_t* __restrict__ xk, ushort_t* __restrict__ xv,
    ushort_t* __restrict__ xa, ushort_t* __restrict__ xg)
{
  const int m = blockIdx.x * 4 + (threadIdx.x >> 6);
  const int lane = threadIdx.x & 63;
  const int c0 = lane << 3;
  const size_t idx = (size_t)m * CDIM + c0;
  const bool first = ((m & (TT - 1)) == 0);
  float v[8], p[8];
  *(float4*)&v[0] = *(const float4*)&x[idx];
  *(float4*)&v[4] = *(const float4*)&x[idx + 4];
  if (first) {
#pragma unroll
    for (int j = 0; j < 8; ++j) p[j] = 0.f;
  } else {
    *(float4*)&p[0] = *(const float4*)&x[idx - CDIM];
    *(float4*)&p[4] = *(const float4*)&x[idx - CDIM + 4];
  }
  float s = 0.f, sp = 0.f;
#pragma unroll
  for (int j = 0; j < 8; ++j) { s += v[j]; sp += p[j]; }
  s = wsum64(s); sp = wsum64(sp);
  const float mu = s * (1.f / 512.f), mup = sp * (1.f / 512.f);
  float q = 0.f, qp = 0.f;
#pragma unroll
  for (int j = 0; j < 8; ++j) {
    const float d1 = v[j] - mu, d2 = p[j] - mup;
    q += d1 * d1; qp += d2 * d2;
  }
  q = wsum64(q); qp = wsum64(qp);
  const float is = rsqrtf(q * (1.f / 512.f) + 1e-5f);
  const float isp = rsqrtf(qp * (1.f / 512.f) + 1e-5f);
  float wc[8], bc[8];
  *(float4*)&wc[0] = *(const float4*)&w[c0]; *(float4*)&wc[4] = *(const float4*)&w[c0 + 4];
  *(float4*)&bc[0] = *(const float4*)&b[c0]; *(float4*)&bc[4] = *(const float4*)&b[c0 + 4];
  float hv[8], dx[8];
#pragma unroll
  for (int j = 0; j < 8; ++j) {
    hv[j] = (v[j] - mu) * is * wc[j] + bc[j];
    const float hp = first ? 0.f : (p[j] - mup) * isp * wc[j] + bc[j];
    dx[j] = hp - hv[j];
  }
  ushort_t* outs[6] = {xr, xw, xk, xv, xa, xg};
#pragma unroll
  for (int o = 0; o < 6; ++o) {
    float mc[8];
    *(float4*)&mc[0] = *(const float4*)&xml[o * CDIM + c0];
    *(float4*)&mc[4] = *(const float4*)&xml[o * CDIM + c0 + 4];
    bf16x8 pk;
#pragma unroll
    for (int j = 0; j < 8; ++j) pk[j] = (short)f2bf(fmaf(dx[j], mc[j], hv[j]));
    *(bf16x8*)&outs[o][idx] = pk;
  }
}

__global__ __launch_bounds__(256) void lnmix1_k(
    const float* __restrict__ x, const float* __restrict__ w,
    const float* __restrict__ b, const float* __restrict__ coef,
    ushort_t* __restrict__ kf)
{
  const int m = blockIdx.x * 4 + (threadIdx.x >> 6);
  const int lane = threadIdx.x & 63;
  const int c0 = lane << 3;
  const size_t idx = (size_t)m * CDIM + c0;
  const bool first = ((m & (TT - 1)) == 0);
  float v[8], p[8];
  *(float4*)&v[0] = *(const float4*)&x[idx];
  *(float4*)&v[4] = *(const float4*)&x[idx + 4];
  if (first) {
#pragma unroll
    for (int j = 0; j < 8; ++j) p[j] = 0.f;
  } else {
    *(float4*)&p[0] = *(const float4*)&x[idx - CDIM];
    *(float4*)&p[4] = *(const float4*)&x[idx - CDIM + 4];
  }
  float s = 0.f, sp = 0.f;
#pragma unroll
  for (int j = 0; j < 8; ++j) { s += v[j]; sp += p[j]; }
  s = wsum64(s); sp = wsum64(sp);
  const float mu = s * (1.f / 512.f), mup = sp * (1.f / 512.f);
  float q = 0.f, qp = 0.f;
#pragma unroll
  for (int j = 0; j < 8; ++j) {
    const float d1 = v[j] - mu, d2 = p[j] - mup;
    q += d1 * d1; qp += d2 * d2;
  }
  q = wsum64(q); qp = wsum64(qp);
  const float is = rsqrtf(q * (1.f / 512.f) + 1e-5f);
  const float isp = rsqrtf(qp * (1.f / 512.f) + 1e-5f);
  bf16x8 pk;
#pragma unroll
  for (int j = 0; j < 8; ++j) {
    const float wc = w[c0 + j], bc = b[c0 + j];
    const float hv = (v[j] - mu) * is * wc + bc;
    const float hp = first ? 0.f : (p[j] - mup) * isp * wc + bc;
    pk[j] = (short)f2bf(fmaf(hp - hv, coef[c0 + j], hv));
  }
  *(bf16x8*)&kf[idx] = pk;
}

__global__ __launch_bounds__(256) void prep_k(
    float* __restrict__ k, const float* __restrict__ a,
    const float* __restrict__ kkp, const float* __restrict__ kap,
    float* __restrict__ aa, float* __restrict__ bb)
{
  const int m = blockIdx.x * 4 + (threadIdx.x >> 6);
  const int lane = threadIdx.x & 63;
  const int c0 = lane << 3;
  const size_t idx = (size_t)m * CDIM + c0;
  float kv[8], av[8], kp[8], ka[8];
  *(float4*)&kv[0] = *(const float4*)&k[idx];     *(float4*)&kv[4] = *(const float4*)&k[idx + 4];
  *(float4*)&av[0] = *(const float4*)&a[idx];     *(float4*)&av[4] = *(const float4*)&a[idx + 4];
  *(float4*)&kp[0] = *(const float4*)&kkp[c0];    *(float4*)&kp[4] = *(const float4*)&kkp[c0 + 4];
  *(float4*)&ka[0] = *(const float4*)&kap[c0];    *(float4*)&ka[4] = *(const float4*)&kap[c0 + 4];
  float kk[8], ss = 0.f;
#pragma unroll
  for (int j = 0; j < 8; ++j) { kk[j] = kv[j] * kp[j]; ss += kk[j] * kk[j]; }
  ss = gsum8(ss);
  const float rden = 1.f / fmaxf(sqrtf(ss), 1e-12f);
  float oaa[8], obb[8], okk[8];
#pragma unroll
  for (int j = 0; j < 8; ++j) {
    const float kkn = kk[j] * rden;
    oaa[j] = -kkn;
    obb[j] = kkn * av[j];
    okk[j] = kv[j] * (1.f + (av[j] - 1.f) * ka[j]);
  }
  *(float4*)&aa[idx] = *(float4*)&oaa[0]; *(float4*)&aa[idx + 4] = *(float4*)&oaa[4];
  *(float4*)&bb[idx] = *(float4*)&obb[0]; *(float4*)&bb[idx + 4] = *(float4*)&obb[4];
  *(float4*)&k[idx]  = *(float4*)&okk[0]; *(float4*)&k[idx + 4]  = *(float4*)&okk[4];
}

__global__ __launch_bounds__(256) void post_k(
    const float* __restrict__ o, const float* __restrict__ r,
    const float* __restrict__ k, const float* __restrict__ v,
    const float* __restrict__ g, const float* __restrict__ gw,
    const float* __restrict__ gb, const float* __restrict__ rkp,
    ushort_t* __restrict__ og)
{
  const int m = blockIdx.x * 4 + (threadIdx.x >> 6);
  const int lane = threadIdx.x & 63;
  const int c0 = lane << 3;
  const size_t idx = (size_t)m * CDIM + c0;
  float ov[8], rv[8], kv[8], vv[8], gv[8], rp[8];
  *(float4*)&ov[0] = *(const float4*)&o[idx];   *(float4*)&ov[4] = *(const float4*)&o[idx + 4];
  *(float4*)&rv[0] = *(const float4*)&r[idx];   *(float4*)&rv[4] = *(const float4*)&r[idx + 4];
  *(float4*)&kv[0] = *(const float4*)&k[idx];   *(float4*)&kv[4] = *(const float4*)&k[idx + 4];
  *(float4*)&vv[0] = *(const float4*)&v[idx];   *(float4*)&vv[4] = *(const float4*)&v[idx + 4];
  *(float4*)&gv[0] = *(const float4*)&g[idx];   *(float4*)&gv[4] = *(const float4*)&g[idx + 4];
  *(float4*)&rp[0] = *(const float4*)&rkp[c0];  *(float4*)&rp[4] = *(const float4*)&rkp[c0 + 4];
  float s = 0.f, dot = 0.f;
#pragma unroll
  for (int j = 0; j < 8; ++j) { s += ov[j]; dot += rv[j] * kv[j] * rp[j]; }
  s = gsum8(s); dot = gsum8(dot);
  const float mu = s * (1.f / 64.f);
  float q = 0.f;
#pragma unroll
  for (int j = 0; j < 8; ++j) { const float d = ov[j] - mu; q += d * d; }
  q = gsum8(q);
  const float is = rsqrtf(q * (1.f / 64.f) + 64e-5f);
  bf16x8 pk;
#pragma unroll
  for (int j = 0; j < 8; ++j) {
    const float gn = (ov[j] - mu) * is * gw[c0 + j] + gb[c0 + j];
    pk[j] = (short)f2bf((gn + dot * vv[j]) * gv[j]);
  }
  *(bf16x8*)&og[idx] = pk;
}

__global__ __launch_bounds__(512) void ln_final_k(
    const float* __restrict__ x, const float* __restrict__ w,
    const float* __restrict__ b, float* __restrict__ out)
{
  const int m = blockIdx.x, c = threadIdx.x;
  const size_t idx = (size_t)m * CDIM + c;
  const float v = x[idx];
  __shared__ float red[8], red2[8];
  float s = wsum64(v);
  if ((c & 63) == 0) red[c >> 6] = s;
  __syncthreads();
  float tot = 0.f;
#pragma unroll
  for (int u = 0; u < 8; ++u) tot += red[u];
  const float mu = tot * (1.f / 512.f);
  const float dv = v - mu;
  float s2 = wsum64(dv * dv);
  if ((c & 63) == 0) red2[c >> 6] = s2;
  __syncthreads();
  float vt = 0.f;
#pragma unroll
  for (int u = 0; u < 8; ++u) vt += red2[u];
  const float y = dv * rsqrtf(vt * (1.f / 512.f) + 1e-5f) * w[c] + b[c];
  const int bidx = m >> 10, t = m & 1023;
  const int p = t & 127, eb = bidx * 8 + (t >> 7);
  out[((size_t)eb * CDIM + c) * 128 + p] = y;
}

__global__ __launch_bounds__(512) void build_x_k(
    const float* __restrict__ img, const float* __restrict__ pos,
    float* __restrict__ x)
{
  const int m = blockIdx.x, c = threadIdx.x;
  const int bidx = m >> 10, t = m & 1023;
  const int p = t & 127, eb = bidx * 8 + (t >> 7);
  x[(size_t)m * CDIM + c] =
      img[((size_t)eb * CDIM + c) * 128 + p] + pos[(size_t)p * CDIM + c];
}

// ---------------------------------------------------------------------------
// Chunked RWKV7 scan. scan1: per chunk (LC=64), from S=0/P=I, per step emit
// o_local_t = Q_t r_t and y_t = P_t r_t; at end store P,Q for scan2.
// Thread (rg=tid>>4, cg=tid&15) owns 4x4 sub-tile; DPP row-reduce.
// ---------------------------------------------------------------------------
__global__ __launch_bounds__(256) void scan1_k(
    const float* __restrict__ r, const float* __restrict__ d,
    const float* __restrict__ k, const float* __restrict__ v,
    const float* __restrict__ aa, const float* __restrict__ bb,
    float* __restrict__ P, float* __restrict__ Q,
    float* __restrict__ Y, float* __restrict__ o)
{
  const int ch = blockIdx.x, bh = blockIdx.y;
  const int b = bh >> 3, hh = bh & 7;
  const int tid = threadIdx.x;
  const int rg = tid >> 4, cg = tid & 15;
  const int r0 = rg << 2, c0 = cg << 2;
  float S[16], Pr[16];
#pragma unroll
  for (int ri = 0; ri < 4; ++ri)
#pragma unroll
    for (int cj = 0; cj < 4; ++cj) {
      S[ri * 4 + cj] = 0.f;
      Pr[ri * 4 + cj] = (r0 + ri == c0 + cj) ? 1.f : 0.f;
    }

  __shared__ float sbuf[3][6 * TB * 64];   // 36 KB
  const size_t base = (size_t)b * TT * CDIM + (size_t)ch * LC * CDIM + hh * 64;
  const float* srcs[6] = {r, d, k, v, aa, bb};
  const int f0 = tid, f1 = tid + 256, f2 = tid + 512;
  const float* gp0 = srcs[f0 >> 7] + base + (size_t)((f0 >> 4) & 7) * CDIM + ((f0 & 15) << 2);
  const float* gp1 = srcs[f1 >> 7] + base + (size_t)((f1 >> 4) & 7) * CDIM + ((f1 & 15) << 2);
  const float* gp2 = srcs[f2 >> 7] + base + (size_t)((f2 >> 4) & 7) * CDIM + ((f2 & 15) << 2);
  const size_t pqbase = ((size_t)(bh * NCH + ch)) * 4096;
  const size_t ybase0 = ((size_t)(bh * NCH + ch)) * (LC * 64);

#define STAGE1(bf_, goff_)                          \
  {                                                 \
    glds16(gp0 + (goff_), &sbuf[bf_][f0 << 2]);     \
    glds16(gp1 + (goff_), &sbuf[bf_][f1 << 2]);     \
    glds16(gp2 + (goff_), &sbuf[bf_][f2 << 2]);     \
  }

#define CGRP1(bf_, g_)                                                          \
  {                                                                             \
    const float* sb0 = sbuf[bf_];                                               \
    const size_t obase = base + (size_t)(g_) * TB * CDIM;                       \
    const size_t ybase = ybase0 + (size_t)(g_) * TB * 64;                       \
    _Pragma("unroll") for (int tt = 0; tt < TB; ++tt) {                         \
      const float* sr  = sb0 + 0 * TB * 64 + tt * 64;                           \
      const float* sd  = sb0 + 1 * TB * 64 + tt * 64;                           \
      const float* sk  = sb0 + 2 * TB * 64 + tt * 64;                           \
      const float* sv  = sb0 + 3 * TB * 64 + tt * 64;                           \
      const float* sa  = sb0 + 4 * TB * 64 + tt * 64;                           \
      const float* sbv = sb0 + 5 * TB * 64 + tt * 64;                           \
      const float4 a4 = *(const float4*)(sa + c0);                              \
      const float4 d4 = *(const float4*)(sd + c0);                              \
      const float4 k4 = *(const float4*)(sk + c0);                              \
      const float4 b4 = *(const float4*)(sbv + c0);                             \
      const float4 r4 = *(const float4*)(sr + c0);                              \
      const float4 v4 = *(const float4*)(sv + r0);                              \
      const float dd[4] = {d4.x, d4.y, d4.z, d4.w};                             \
      const float ak[4] = {a4.x, a4.y, a4.z, a4.w};                             \
      const float kc[4] = {k4.x, k4.y, k4.z, k4.w};                             \
      const float bc2[4] = {b4.x, b4.y, b4.z, b4.w};                            \
      const float rr[4] = {r4.x, r4.y, r4.z, r4.w};                             \
      const float vr[4] = {v4.x, v4.y, v4.z, v4.w};                             \
      float ps[4], pp[4];                                                       \
      _Pragma("unroll") for (int ri = 0; ri < 4; ++ri) {                        \
        ps[ri] = fmaf(S[ri*4+0], ak[0], fmaf(S[ri*4+1], ak[1],                  \
                 fmaf(S[ri*4+2], ak[2], S[ri*4+3] * ak[3])));                   \
        pp[ri] = fmaf(Pr[ri*4+0], ak[0], fmaf(Pr[ri*4+1], ak[1],                \
                 fmaf(Pr[ri*4+2], ak[2], Pr[ri*4+3] * ak[3])));                 \
      }                                                                         \
      _Pragma("unroll") for (int ri = 0; ri < 4; ++ri) {                        \
        ps[ri] = rowsum16(ps[ri]);                                              \
        pp[ri] = rowsum16(pp[ri]);                                              \
      }                                                                         \
      float yv[4], ol[4];                                                       \
      _Pragma("unroll") for (int ri = 0; ri < 4; ++ri) {                        \
        float yacc = 0.f, oacc = 0.f;                                           \
        _Pragma("unroll") for (int cj = 0; cj < 4; ++cj) {                      \
          const float sn = fmaf(S[ri*4+cj], dd[cj],                             \
                           fmaf(ps[ri], bc2[cj], vr[ri] * kc[cj]));             \
          const float pn = fmaf(Pr[ri*4+cj], dd[cj], pp[ri] * bc2[cj]);         \
          S[ri*4+cj] = sn;                                                      \
          Pr[ri*4+cj] = pn;                                                     \
          oacc = fmaf(sn, rr[cj], oacc);                                        \
          yacc = fmaf(pn, rr[cj], yacc);                                        \
        }                                                                       \
        ol[ri] = oacc; yv[ri] = yacc;                                           \
      }                                                                         \
      _Pragma("unroll") for (int ri = 0; ri < 4; ++ri) {                        \
        ol[ri] = rowsum16(ol[ri]);                                              \
        yv[ri] = rowsum16(yv[ri]);                                              \
      }                                                                         \
      if (cg == 0) {                                                            \
        *(float4*)&o[obase + (size_t)tt * CDIM + r0] =                          \
            make_float4(ol[0], ol[1], ol[2], ol[3]);                            \
        *(float4*)&Y[ybase + (size_t)tt * 64 + r0] =                            \
            make_float4(yv[0], yv[1], yv[2], yv[3]);                            \
      }                                                                         \
    }                                                                           \
  }

  constexpr int NG = LC / TB;   // 8
  STAGE1(0, 0);
  STAGE1(1, (size_t)TB * CDIM);
  int bc = 0, bs = 2;
  for (int g = 0; g + 1 < NG; ++g) {
    asm volatile("s_waitcnt vmcnt(3)" ::: "memory");
    __builtin_amdgcn_s_barrier();
    if (g + 2 < NG) {
      STAGE1(bs, (size_t)(g + 2) * TB * CDIM);
      bs = (bs == 2) ? 0 : bs + 1;
    }
    CGRP1(bc, g);
    bc = (bc == 2) ? 0 : bc + 1;
  }
  asm volatile("s_waitcnt vmcnt(0)" ::: "memory");
  __builtin_amdgcn_s_barrier();
  CGRP1(bc, NG - 1);
#undef STAGE1
#undef CGRP1

  const size_t ob = pqbase + (size_t)r0 * 64 + c0;
#pragma unroll
  for (int ri = 0; ri < 4; ++ri) {
    *(float4*)&Q[ob + ri * 64] = make_float4(S[ri*4+0], S[ri*4+1], S[ri*4+2], S[ri*4+3]);
    *(float4*)&P[ob + ri * 64] = make_float4(Pr[ri*4+0], Pr[ri*4+1], Pr[ri*4+2], Pr[ri*4+3]);
  }
}

// scan2: sequential chunk composition; P AND Q register-prefetched one
// compose ahead so no global-load latency sits on the critical path.
__global__ __launch_bounds__(512) void scan2_k(
    const float* __restrict__ P, const float* __restrict__ Q,
    float* __restrict__ Sst)
{
  const int tid = threadIdx.x;
  const int f0 = tid << 2;
  const int r0 = tid >> 4;
  const int c0 = (tid & 15) << 2;
  __shared__ float sP[4096];
  __shared__ float sS[4096];
  float4 S0 = {0.f, 0.f, 0.f, 0.f}, S1 = {0.f, 0.f, 0.f, 0.f};
  const size_t cbase = (size_t)blockIdx.x * NCH * 4096;
  float4 pf0 = *(const float4*)&P[cbase + f0];
  float4 pf1 = *(const float4*)&P[cbase + f0 + 2048];
  float4 qf0 = *(const float4*)&Q[cbase + f0];
  float4 qf1 = *(const float4*)&Q[cbase + f0 + 2048];

  for (int c = 0; c < NCH; ++c) {
    const size_t cb = cbase + (size_t)c * 4096;
    *(float4*)&Sst[cb + f0] = S0;
    *(float4*)&Sst[cb + f0 + 2048] = S1;
    __syncthreads();
    *(float4*)&sP[f0] = pf0;  *(float4*)&sP[f0 + 2048] = pf1;
    *(float4*)&sS[f0] = S0;   *(float4*)&sS[f0 + 2048] = S1;
    __syncthreads();
    const float4 q0 = qf0, q1 = qf1;
    if (c + 1 < NCH) {
      pf0 = *(const float4*)&P[cb + 4096 + f0];
      pf1 = *(const float4*)&P[cb + 4096 + f0 + 2048];
      qf0 = *(const float4*)&Q[cb + 4096 + f0];
      qf1 = *(const float4*)&Q[cb + 4096 + f0 + 2048];
    }

    float a00 = 0.f, a01 = 0.f, a02 = 0.f, a03 = 0.f;
    float a10 = 0.f, a11 = 0.f, a12 = 0.f, a13 = 0.f;
    const float* sS0 = &sS[r0 * 64];
    const float* sS1 = &sS[(r0 + 32) * 64];
#pragma unroll
    for (int mm = 0; mm < 64; ++mm) {
      const float4 p4 = *(const float4*)&sP[mm * 64 + c0];
      const float u0 = sS0[mm], u1 = sS1[mm];
      a00 = fmaf(u0, p4.x, a00); a01 = fmaf(u0, p4.y, a01);
      a02 = fmaf(u0, p4.z, a02); a03 = fmaf(u0, p4.w, a03);
      a10 = fmaf(u1, p4.x, a10); a11 = fmaf(u1, p4.y, a11);
      a12 = fmaf(u1, p4.z, a12); a13 = fmaf(u1, p4.w, a13);
    }
    S0.x = a00 + q0.x; S0.y = a01 + q0.y; S0.z = a02 + q0.z; S0.w = a03 + q0.w;
    S1.x = a10 + q1.x; S1.y = a11 + q1.y; S1.z = a12 + q1.z; S1.w = a13 + q1.w;
  }
}

// corr: o[t][i] += sum_j Sst[i][j] * Y[t][j]  (one LC=64 chunk per block).
__global__ __launch_bounds__(256) void corr_k(
    const float* __restrict__ Sst, const float* __restrict__ Y,
    float* __restrict__ o)
{
  const int ch = blockIdx.x, bh = blockIdx.y;
  const int b = bh >> 3, hh = bh & 7;
  const int tid = threadIdx.x;
  __shared__ float ST[64][68];   // ST[j][i] = Sst[i][j]
  __shared__ float Yl[64][68];   // Yl[t][j]
  const size_t cb = ((size_t)(bh * NCH + ch)) * 4096;
#pragma unroll
  for (int u = 0; u < 16; ++u) {
    const int idx = tid + 256 * u;
    ST[idx & 63][idx >> 6] = Sst[cb + idx];
  }
#pragma unroll
  for (int u = 0; u < 4; ++u) {
    const int fi = tid + 256 * u;              // float4 index 0..1023
    *(float4*)&Yl[fi >> 4][(fi & 15) << 2] = *(const float4*)&Y[cb + (size_t)fi * 4];
  }
  __syncthreads();
  const int t = tid >> 2, q = tid & 3, i0 = q << 4;
  f32x4 acc[4];
#pragma unroll
  for (int u = 0; u < 4; ++u) acc[u] = (f32x4){0.f, 0.f, 0.f, 0.f};
  const float* yrow = &Yl[t][0];
#pragma unroll 4
  for (int j = 0; j < 64; ++j) {
    const float yv = yrow[j];
#pragma unroll
    for (int u = 0; u < 4; ++u) {
      const f32x4 s4 = *(const f32x4*)&ST[j][i0 + 4 * u];
      acc[u] = {fmaf(yv, s4[0], acc[u][0]), fmaf(yv, s4[1], acc[u][1]),
                fmaf(yv, s4[2], acc[u][2]), fmaf(yv, s4[3], acc[u][3])};
    }
  }
  const size_t obase = (size_t)b * TT * CDIM + (size_t)ch * LC * CDIM + hh * 64 +
                       (size_t)t * CDIM + i0;
#pragma unroll
  for (int u = 0; u < 4; ++u) {
    float4 cur = *(const float4*)&o[obase + 4 * u];
    cur.x += acc[u][0]; cur.y += acc[u][1]; cur.z += acc[u][2]; cur.w += acc[u][3];
    *(float4*)&o[obase + 4 * u] = cur;
  }
}

// ---------------------------------------------------------------------------
extern "C" void kernel_launch(void* const* d_in, const int* in_sizes, int n_in,
                              void* d_out, int out_size, void* d_ws, size_t ws_size,
                              hipStream_t stream) {
  (void)in_sizes; (void)n_in; (void)out_size; (void)ws_size;
  const float* img  = (const float*)d_in[0];
  const float* pos  = (const float*)d_in[1];
  const float* xm   = (const float*)d_in[2];
  const float* w0   = (const float*)d_in[3];
  const float* w1   = (const float*)d_in[4];
  const float* w2   = (const float*)d_in[5];
  const float* a0   = (const float*)d_in[6];
  const float* a1   = (const float*)d_in[7];
  const float* a2   = (const float*)d_in[8];
  const float* v0   = (const float*)d_in[9];
  const float* v1   = (const float*)d_in[10];
  const float* v2   = (const float*)d_in[11];
  const float* g1   = (const float*)d_in[12];
  const float* g2   = (const float*)d_in[13];
  const float* kkp  = (const float*)d_in[14];
  const float* kap  = (const float*)d_in[15];
  const float* rkp  = (const float*)d_in[16];
  const float* Wr   = (const float*)d_in[17];
  const float* Wk   = (const float*)d_in[18];
  const float* Wv   = (const float*)d_in[19];
  const float* Wo   = (const float*)d_in[20];
  const float* lnxw = (const float*)d_in[21];
  const float* lnxb = (const float*)d_in[22];
  const float* ln1w = (const float*)d_in[23];
  const float* ln1b = (const float*)d_in[24];
  const float* ln2w = (const float*)d_in[25];
  const float* ln2b = (const float*)d_in[26];
  const float* fxk  = (const float*)d_in[27];
  const float* Wkey = (const float*)d_in[28];
  const float* Wval = (const float*)d_in[29];
  const float* lnfw = (const float*)d_in[30];
  const float* lnfb = (const float*)d_in[31];

  float* ws = (float*)d_ws;
  const size_t SZ = (size_t)NTOK * CDIM;   // 2M elements
  float* x   = ws + 0 * SZ;
  float* r_  = ws + 2 * SZ;
  float* dec = ws + 3 * SZ;
  float* k_  = ws + 4 * SZ;
  float* v_  = ws + 5 * SZ;
  float* vf  = ws + 6 * SZ;
  float* a_  = ws + 7 * SZ;
  float* g_  = ws + 8 * SZ;
  float* aa  = ws + 9 * SZ;
  float* bb  = ws + 10 * SZ;
  float* o_  = ws + 11 * SZ;
  float* mixf = ws + 12 * SZ;
  ushort_t* xr = (ushort_t*)mixf;
  ushort_t* xw = xr + SZ;
  ushort_t* xk = xr + 2 * SZ;
  ushort_t* xv = xr + 3 * SZ;
  ushort_t* xa = xr + 4 * SZ;
  ushort_t* xg = xr + 5 * SZ;
  float* Pbuf = mixf;
  float* Qbuf = mixf + SZ;
  float* Sst  = mixf + 2 * SZ;
  ushort_t* tmpb = (ushort_t*)(ws + 15 * SZ);            // 4096 x 288 bf16
  ushort_t* t0b = tmpb;
  ushort_t* t1b = tmpb + (size_t)NTOK * 64;
  ushort_t* t2b = tmpb + (size_t)NTOK * 128;
  ushort_t* t3b = tmpb + (size_t)NTOK * 160;
  ushort_t* tfb  = (ushort_t*)(ws + 15 * SZ + SZ / 2);   // 4096 x 2048 bf16
  float* Ybuf = ws + 16 * SZ;    // aliases tfb interior; dead during time-mix
  ushort_t* ogb  = (ushort_t*)(ws + 17 * SZ + SZ / 2);   // 4096 x 512 bf16
  ushort_t* wb   = (ushort_t*)(ws + 18 * SZ);            // bf16 weights

  const size_t oWr  = 0;
  const size_t oWk  = oWr  + (size_t)8 * 512 * 512;
  const size_t oWv  = oWk  + (size_t)8 * 512 * 512;
  const size_t oWo  = oWv  + (size_t)8 * 512 * 512;
  const size_t oW1  = oWo  + (size_t)8 * 512 * 512;
  const size_t oW2  = oW1  + (size_t)8 * 128 * 512;
  const size_t oA1  = oW2  + (size_t)8 * 512 * 64;
  const size_t oA2  = oA1  + (size_t)8 * 128 * 512;
  const size_t oV1  = oA2  + (size_t)8 * 512 * 64;
  const size_t oV2  = oV1  + (size_t)8 * 128 * 512;
  const size_t oG1  = oV2  + (size_t)8 * 512 * 32;
  const size_t oG2  = oG1  + (size_t)8 * 128 * 512;
  const size_t oKey = oG2  + (size_t)8 * 512 * 128;
  const size_t oVal = oKey + (size_t)8 * 2048 * 512;

#define WPREP(src, dst, K_, N_, NP_) \
  wprep_k<<<dim3((NP_) / 32, (K_) / 32, 8), 256, 0, stream>>>(src, dst, K_, N_, NP_)
  WPREP(Wr,   wb + oWr,  512, 512, 512);
  WPREP(Wk,   wb + oWk,  512, 512, 512);
  WPREP(Wv,   wb + oWv,  512, 512, 512);
  WPREP(Wo,   wb + oWo,  512, 512, 512);
  WPREP(w1,   wb + oW1,  512, 64,  128);
  WPREP(w2,   wb + oW2,  64,  512, 512);
  WPREP(a1,   wb + oA1,  512, 64,  128);
  WPREP(a2,   wb + oA2,  64,  512, 512);
  WPREP(v1,   wb + oV1,  512, 32,  128);
  WPREP(v2,   wb + oV2,  32,  512, 512);
  WPREP(g1,   wb + oG1,  512, 128, 128);
  WPREP(g2,   wb + oG2,  128, 512, 512);
  WPREP(Wkey, wb + oKey, 512, 2048, 2048);
  WPREP(Wval, wb + oVal, 2048, 512, 512);
#undef WPREP

  build_x_k<<<NTOK, 512, 0, stream>>>(img, pos, x);

  for (int l = 0; l < 8; ++l) {
    const size_t lc = (size_t)l * CDIM;
    const float* xml = xm + (size_t)l * 6 * CDIM;
    const ushort_t* bWr = wb + oWr + (size_t)l * 512 * 512;
    const ushort_t* bWk = wb + oWk + (size_t)l * 512 * 512;
    const ushort_t* bWv = wb + oWv + (size_t)l * 512 * 512;
    const ushort_t* bWo = wb + oWo + (size_t)l * 512 * 512;
    const ushort_t* bW1 = wb + oW1 + (size_t)l * 128 * 512;
    const ushort_t* bW2 = wb + oW2 + (size_t)l * 512 * 64;
    const ushort_t* bA1 = wb + oA1 + (size_t)l * 128 * 512;
    const ushort_t* bA2 = wb + oA2 + (size_t)l * 512 * 64;
    const ushort_t* bV1 = wb + oV1 + (size_t)l * 128 * 512;
    const ushort_t* bV2 = wb + oV2 + (size_t)l * 512 * 32;
    const ushort_t* bG1 = wb + oG1 + (size_t)l * 128 * 512;
    const ushort_t* bG2 = wb + oG2 + (size_t)l * 512 * 128;
    const ushort_t* bKy = wb + oKey + (size_t)l * 2048 * 512;
    const ushort_t* bVl = wb + oVal + (size_t)l * 512 * 2048;
    float* vdst = (l == 0) ? vf : v_;

    // ---- time mix ----
    lnmix6_k<<<NTOK / 4, 256, 0, stream>>>(x, ln1w + lc, ln1b + lc, xml,
                                           xr, xw, xk, xv, xa, xg);
    Segs4 qkv;
    qkv.s[0] = {xr, bWr, r_,   0, 0, 512, 512, EPI_NONE, 0};
    qkv.s[1] = {xk, bWk, k_,   0, 0, 512, 512, EPI_NONE, 0};
    qkv.s[2] = {xv, bWv, vdst, 0, 0, 512, 512, EPI_NONE, 0};
    qkv.s[3] = {0, 0, 0, 0, 0, 0, 0, -1, 0};
    ggemm_k<64><<<dim3(NTOK / BM, 8, 3), 256, 0, stream>>>(qkv);

    Segs4 dn;
    dn.s[0] = {xw, bW1, t0b, 0, 0, 64,  512, EPI_TANH, 1};
    dn.s[1] = {xa, bA1, t1b, 0, 0, 64,  512, EPI_NONE, 1};
    dn.s[2] = {xv, bV1, t2b, 0, 0, 32,  512, EPI_NONE, 1};
    dn.s[3] = {xg, bG1, t3b, 0, 0, 128, 512, EPI_SIG,  1};
    ggemm_k<64><<<dim3(NTOK / BM, 2, 4), 256, 0, stream>>>(dn);

    Segs4 up;
    up.s[0] = {t0b, bW2, dec, w0 + lc, 0,  512, 64,  EPI_DECAY, 0};
    up.s[1] = {t1b, bA2, a_,  a0 + lc, 0,  512, 64,  EPI_SIGB,  0};
    up.s[2] = {t2b, bV2, v_,  v0 + lc, vf, 512, 32,  (l > 0) ? EPI_VMIX : -1, 0};
    up.s[3] = {t3b, bG2, g_,  0, 0,        512, 128, EPI_NONE,  0};
    ggemm_k<64><<<dim3(NTOK / BM, 8, 4), 256, 0, stream>>>(up);

    const float* vptr = (l == 0) ? vf : v_;
    prep_k<<<NTOK / 4, 256, 0, stream>>>(k_, a_, kkp + lc, kap + lc, aa, bb);
    scan1_k<<<dim3(NCH, 32), 256, 0, stream>>>(r_, dec, k_, vptr, aa, bb,
                                               Pbuf, Qbuf, Ybuf, o_);
    scan2_k<<<32, 512, 0, stream>>>(Pbuf, Qbuf, Sst);
    corr_k<<<dim3(NCH, 32), 256, 0, stream>>>(Sst, Ybuf, o_);
    post_k<<<NTOK / 4, 256, 0, stream>>>(o_, r_, k_, vptr, g_, lnxw + lc, lnxb + lc,
                                         rkp + lc, ogb);
    Segs4 wo;
    wo.s[0] = {ogb, bWo, x, 0, 0, 512, 512, EPI_ADD, 0};
    wo.s[1] = wo.s[2] = wo.s[3] = {0, 0, 0, 0, 0, 0, 0, -1, 0};
    ggemm_k<64><<<dim3(NTOK / BM, 8, 1), 256, 0, stream>>>(wo);

    // ---- channel mix ----
    lnmix1_k<<<NTOK / 4, 256, 0, stream>>>(x, ln2w + lc, ln2b + lc, fxk + lc, xr);
    Segs4 f1;
    f1.s[0] = {xr, bKy, tfb, 0, 0, 2048, 512, EPI_RELU2, 1};
    f1.s[1] = f1.s[2] = f1.s[3] = {0, 0, 0, 0, 0, 0, 0, -1, 0};
    ggemm_k<64><<<dim3(NTOK / BM, 32, 1), 256, 0, stream>>>(f1);
    Segs4 f2;
    f2.s[0] = {tfb, bVl, x, 0, 0, 512, 2048, EPI_ADD, 0};
    f2.s[1] = f2.s[2] = f2.s[3] = {0, 0, 0, 0, 0, 0, 0, -1, 0};
    ggemm_k<64><<<dim3(NTOK / BM, 8, 1), 256, 0, stream>>>(f2);
  }

  ln_final_k<<<NTOK, 512, 0, stream>>>(x, lnfw, lnfb, (float*)d_out);
}

// Round 13
// 2173.864 us; speedup vs baseline: 1.1327x; 1.0160x over previous
//
#include <hip/hip_runtime.h>
#include <hip/hip_bf16.h>
#include <math.h>

// ---------------------------------------------------------------------------
// RWKV7 vision block. Pipelined bf16 MFMA GEMMs (3-buf counted-vmcnt) +
// chunked parallel scan (LC=64, row-split x2): scan1 emits P,Q,y,o_local;
// scan2 (P,Q reg-prefetched) composes chunk states; corr adds S_start @ y.
// B=4, T=1024, C=512, H=8, N=64, L=8.
// ---------------------------------------------------------------------------

#define NTOK 4096
#define CDIM 512
#define TT   1024
#define LC   64
#define NCH  16
#define TB   8      // scan time-steps per LDS stage group

#define BM 128
#define BK 32

enum { EPI_NONE=0, EPI_TANH, EPI_SIG, EPI_DECAY, EPI_SIGB, EPI_VMIX, EPI_RELU2, EPI_ADD };

typedef short bf16x8 __attribute__((ext_vector_type(8)));
typedef float f32x4 __attribute__((ext_vector_type(4)));
typedef unsigned short ushort_t;

__device__ __forceinline__ float wsum64(float v) {
#pragma unroll
  for (int s = 1; s < 64; s <<= 1) v += __shfl_xor(v, s);
  return v;
}
__device__ __forceinline__ float gsum8(float v) {
  v += __shfl_xor(v, 1); v += __shfl_xor(v, 2); v += __shfl_xor(v, 4);
  return v;
}
// Sum over the 16 lanes of a DPP row (all lanes receive the total).
__device__ __forceinline__ float rowsum16(float x) {
  int t;
  t = __builtin_amdgcn_mov_dpp(__builtin_bit_cast(int, x), 0x128, 0xF, 0xF, true); // row_ror:8
  x += __builtin_bit_cast(float, t);
  t = __builtin_amdgcn_mov_dpp(__builtin_bit_cast(int, x), 0x124, 0xF, 0xF, true); // row_ror:4
  x += __builtin_bit_cast(float, t);
  t = __builtin_amdgcn_mov_dpp(__builtin_bit_cast(int, x), 0x122, 0xF, 0xF, true); // row_ror:2
  x += __builtin_bit_cast(float, t);
  t = __builtin_amdgcn_mov_dpp(__builtin_bit_cast(int, x), 0x121, 0xF, 0xF, true); // row_ror:1
  x += __builtin_bit_cast(float, t);
  return x;
}
__device__ __forceinline__ float sigm(float z) { return 1.f / (1.f + expf(-z)); }
__device__ __forceinline__ ushort_t f2bf(float x) {
  return __builtin_bit_cast(unsigned short, __float2bfloat16(x));
}
__device__ __forceinline__ void glds16(const void* g, void* l) {
  __builtin_amdgcn_global_load_lds(
      (const __attribute__((address_space(1))) void*)g,
      (__attribute__((address_space(3))) void*)l, 16, 0, 0);
}

// ---------------------------------------------------------------------------
// Grouped bf16 MFMA GEMM:  C[M,N] = epi(A[M,K] @ B[Npad,K]^T), per-z segment.
// ---------------------------------------------------------------------------
struct Seg {
  const ushort_t* A; const ushort_t* B; void* C;
  const float* bias; const float* e1;
  int N; int K; int epi; int obf;
};
struct Segs4 { Seg s[4]; };

template<int BNt>
__global__ __launch_bounds__(256) void ggemm_k(Segs4 segs) {
  const Seg sg = segs.s[blockIdx.z];
  if (sg.epi < 0) return;
  constexpr int NCHK = 8 + BNt / 16;
  constexpr int LPW  = NCHK / 4;
  constexpr int WNF  = BNt / 32;
  __shared__ ushort_t As[3][BM * BK];
  __shared__ ushort_t Bs[3][BNt * BK];
  const ushort_t* __restrict__ A = sg.A;
  const ushort_t* __restrict__ B = sg.B;
  const int N = sg.N, K = sg.K;
  const int tid = threadIdx.x;
  const int wave = tid >> 6, lane = tid & 63;
  const int m0 = blockIdx.x * BM, n0 = blockIdx.y * BNt;
  const int wm = (wave >> 1) << 6, wn = (wave & 1) * (BNt / 2);

  f32x4 zero = {0.f, 0.f, 0.f, 0.f};
  f32x4 acc[4][WNF];
#pragma unroll
  for (int i = 0; i < 4; ++i)
#pragma unroll
    for (int j = 0; j < WNF; ++j) acc[i][j] = zero;

  const int crow = lane >> 2;
  const int soff = (((lane & 3) ^ (crow & 3)) << 3);
  const ushort_t* gptr[LPW];
  ushort_t* lbase[LPW];
  int lstr[LPW];
#pragma unroll
  for (int i = 0; i < LPW; ++i) {
    const int c = wave + 4 * i;
    if (c < 8) {
      gptr[i] = A + (size_t)(m0 + c * 16 + crow) * K + soff;
      lbase[i] = &As[0][c * 512 + lane * 8];
      lstr[i] = BM * BK;
    } else {
      gptr[i] = B + (size_t)(n0 + (c - 8) * 16 + crow) * K + soff;
      lbase[i] = &Bs[0][(c - 8) * 512 + lane * 8];
      lstr[i] = BNt * BK;
    }
  }

#define STAGE(bf_, k0_)                                        \
  { _Pragma("unroll") for (int i = 0; i < LPW; ++i)            \
      glds16(gptr[i] + (k0_), lbase[i] + (bf_) * lstr[i]); }

  const int rA = wm + (lane & 15);
  const int rB = wn + (lane & 15);
  const int kb = (((lane >> 4) ^ (lane & 3)) << 3);

#define COMPUTE(bf_)                                                          \
  {                                                                           \
    bf16x8 av[4], bvv[WNF];                                                   \
    _Pragma("unroll") for (int f = 0; f < 4; ++f)                             \
      av[f] = *(const bf16x8*)(&As[bf_][(rA + f * 16) * 32 + kb]);            \
    _Pragma("unroll") for (int f = 0; f < WNF; ++f)                           \
      bvv[f] = *(const bf16x8*)(&Bs[bf_][(rB + f * 16) * 32 + kb]);           \
    _Pragma("unroll") for (int i = 0; i < 4; ++i)                             \
      _Pragma("unroll") for (int j = 0; j < WNF; ++j)                         \
        acc[i][j] = __builtin_amdgcn_mfma_f32_16x16x32_bf16(av[i], bvv[j],    \
                                                            acc[i][j], 0, 0, 0); \
  }

  const int nk = K / BK;
  STAGE(0, 0);
  if (nk > 1) STAGE(1, BK);
  int bc = 0, bs = 2;
  for (int k = 0; k + 1 < nk; ++k) {
    asm volatile("s_waitcnt vmcnt(%0)" :: "i"(LPW) : "memory");
    __builtin_amdgcn_s_barrier();
    if (k + 2 < nk) {
      STAGE(bs, (k + 2) * BK);
      bs = (bs == 2) ? 0 : bs + 1;
    }
    COMPUTE(bc);
    bc = (bc == 2) ? 0 : bc + 1;
  }
  asm volatile("s_waitcnt vmcnt(0)" ::: "memory");
  __builtin_amdgcn_s_barrier();
  COMPUTE(bc);
#undef STAGE
#undef COMPUTE

  void* Cout = sg.C;
  const float* bias = sg.bias;
  const float* e1 = sg.e1;
  const int em = m0 + wm + ((lane >> 4) << 2);
  const int en = n0 + wn + (lane & 15);

#define EPI_STORE(EPI_, OBF_)                                                 \
  { _Pragma("unroll") for (int fi = 0; fi < 4; ++fi) {                        \
      _Pragma("unroll") for (int fj = 0; fj < WNF; ++fj) {                    \
        const int gn = en + fj * 16;                                          \
        if (gn < N) {                                                         \
          _Pragma("unroll") for (int rr = 0; rr < 4; ++rr) {                  \
            const int gm = em + fi * 16 + rr;                                 \
            const size_t idx = (size_t)gm * N + gn;                           \
            const float y = acc[fi][fj][rr];                                  \
            float outv;                                                       \
            if (EPI_ == EPI_NONE) { outv = y; }                               \
            else if (EPI_ == EPI_TANH) { outv = tanhf(y); }                   \
            else if (EPI_ == EPI_SIG) { outv = sigm(y); }                     \
            else if (EPI_ == EPI_DECAY) {                                     \
              const float z = bias[gn] + y;                                   \
              const float w = -log1pf(expf(-z)) - 0.5f;                       \
              outv = expf(-expf(w));                                          \
            } else if (EPI_ == EPI_SIGB) { outv = sigm(bias[gn] + y); }       \
            else if (EPI_ == EPI_VMIX) {                                      \
              const float vr = ((float*)Cout)[idx];                           \
              outv = vr + (e1[idx] - vr) * sigm(bias[gn] + y);                \
            } else if (EPI_ == EPI_RELU2) {                                   \
              const float t = fmaxf(y, 0.f); outv = t * t;                    \
            } else { outv = ((float*)Cout)[idx] + y; }                        \
            if (OBF_) ((ushort_t*)Cout)[idx] = f2bf(outv);                    \
            else      ((float*)Cout)[idx] = outv;                             \
          }                                                                   \
        }                                                                     \
      } } }

  switch (sg.epi) {
    case EPI_NONE:  if (sg.obf) EPI_STORE(EPI_NONE, 1) else EPI_STORE(EPI_NONE, 0); break;
    case EPI_TANH:  EPI_STORE(EPI_TANH, 1); break;
    case EPI_SIG:   EPI_STORE(EPI_SIG, 1); break;
    case EPI_DECAY: EPI_STORE(EPI_DECAY, 0); break;
    case EPI_SIGB:  EPI_STORE(EPI_SIGB, 0); break;
    case EPI_VMIX:  EPI_STORE(EPI_VMIX, 0); break;
    case EPI_RELU2: EPI_STORE(EPI_RELU2, 1); break;
    case EPI_ADD:   EPI_STORE(EPI_ADD, 0); break;
  }
#undef EPI_STORE
}

// ---------------------------------------------------------------------------
// Weight prep: fp32 [L][K][N] -> bf16 [L][Npad][K] (transposed, zero-padded).
// ---------------------------------------------------------------------------
__global__ __launch_bounds__(256) void wprep_k(
    const float* __restrict__ in, ushort_t* __restrict__ out,
    int K, int N, int Npad)
{
  __shared__ float t[32][33];
  const int l = blockIdx.z;
  const int n0 = blockIdx.x * 32, k0 = blockIdx.y * 32;
  const int tx = threadIdx.x & 31, ty = threadIdx.x >> 5;
  const float* src = in + (size_t)l * K * N;
  ushort_t* dst = out + (size_t)l * Npad * K;
#pragma unroll
  for (int i = 0; i < 32; i += 8) {
    const int k = k0 + ty + i, n = n0 + tx;
    t[ty + i][tx] = (n < N) ? src[(size_t)k * N + n] : 0.f;
  }
  __syncthreads();
#pragma unroll
  for (int i = 0; i < 32; i += 8) {
    const int n = n0 + ty + i, k = k0 + tx;
    dst[(size_t)n * K + k] = f2bf(t[tx][ty + i]);
  }
}

// ---------------------------------------------------------------------------
// Wave-per-token elementwise. Block=256 (4 waves = 4 tokens); lane owns 8 ch.
// ---------------------------------------------------------------------------
__global__ __launch_bounds__(256) void lnmix6_k(
    const float* __restrict__ x, const float* __restrict__ w,
    const float* __restrict__ b, const float* __restrict__ xml,
    ushort_t* __restrict__ xr, ushort_t* __restrict__ xw,
    ushort_t* __restrict__ xk, ushort_t* __restrict__ xv,
    ushort_t* __restrict__ xa, ushort_t* __restrict__ xg)
{
  const int m = blockIdx.x * 4 + (threadIdx.x >> 6);
  const int lane = threadIdx.x & 63;
  const int c0 = lane << 3;
  const size_t idx = (size_t)m * CDIM + c0;
  const bool first = ((m & (TT - 1)) == 0);
  float v[8], p[8];
  *(float4*)&v[0] = *(const float4*)&x[idx];
  *(float4*)&v[4] = *(const float4*)&x[idx + 4];
  if (first) {
#pragma unroll
    for (int j = 0; j < 8; ++j) p[j] = 0.f;
  } else {
    *(float4*)&p[0] = *(const float4*)&x[idx - CDIM];
    *(float4*)&p[4] = *(const float4*)&x[idx - CDIM + 4];
  }
  float s = 0.f, sp = 0.f;
#pragma unroll
  for (int j = 0; j < 8; ++j) { s += v[j]; sp += p[j]; }
  s = wsum64(s); sp = wsum64(sp);
  const float mu = s * (1.f / 512.f), mup = sp * (1.f / 512.f);
  float q = 0.f, qp = 0.f;
#pragma unroll
  for (int j = 0; j < 8; ++j) {
    const float d1 = v[j] - mu, d2 = p[j] - mup;
    q += d1 * d1; qp += d2 * d2;
  }
  q = wsum64(q); qp = wsum64(qp);
  const float is = rsqrtf(q * (1.f / 512.f) + 1e-5f);
  const float isp = rsqrtf(qp * (1.f / 512.f) + 1e-5f);
  float wc[8], bc[8];
  *(float4*)&wc[0] = *(const float4*)&w[c0]; *(float4*)&wc[4] = *(const float4*)&w[c0 + 4];
  *(float4*)&bc[0] = *(const float4*)&b[c0]; *(float4*)&bc[4] = *(const float4*)&b[c0 + 4];
  float hv[8], dx[8];
#pragma unroll
  for (int j = 0; j < 8; ++j) {
    hv[j] = (v[j] - mu) * is * wc[j] + bc[j];
    const float hp = first ? 0.f : (p[j] - mup) * isp * wc[j] + bc[j];
    dx[j] = hp - hv[j];
  }
  ushort_t* outs[6] = {xr, xw, xk, xv, xa, xg};
#pragma unroll
  for (int o = 0; o < 6; ++o) {
    float mc[8];
    *(float4*)&mc[0] = *(const float4*)&xml[o * CDIM + c0];
    *(float4*)&mc[4] = *(const float4*)&xml[o * CDIM + c0 + 4];
    bf16x8 pk;
#pragma unroll
    for (int j = 0; j < 8; ++j) pk[j] = (short)f2bf(fmaf(dx[j], mc[j], hv[j]));
    *(bf16x8*)&outs[o][idx] = pk;
  }
}

__global__ __launch_bounds__(256) void lnmix1_k(
    const float* __restrict__ x, const float* __restrict__ w,
    const float* __restrict__ b, const float* __restrict__ coef,
    ushort_t* __restrict__ kf)
{
  const int m = blockIdx.x * 4 + (threadIdx.x >> 6);
  const int lane = threadIdx.x & 63;
  const int c0 = lane << 3;
  const size_t idx = (size_t)m * CDIM + c0;
  const bool first = ((m & (TT - 1)) == 0);
  float v[8], p[8];
  *(float4*)&v[0] = *(const float4*)&x[idx];
  *(float4*)&v[4] = *(const float4*)&x[idx + 4];
  if (first) {
#pragma unroll
    for (int j = 0; j < 8; ++j) p[j] = 0.f;
  } else {
    *(float4*)&p[0] = *(const float4*)&x[idx - CDIM];
    *(float4*)&p[4] = *(const float4*)&x[idx - CDIM + 4];
  }
  float s = 0.f, sp = 0.f;
#pragma unroll
  for (int j = 0; j < 8; ++j) { s += v[j]; sp += p[j]; }
  s = wsum64(s); sp = wsum64(sp);
  const float mu = s * (1.f / 512.f), mup = sp * (1.f / 512.f);
  float q = 0.f, qp = 0.f;
#pragma unroll
  for (int j = 0; j < 8; ++j) {
    const float d1 = v[j] - mu, d2 = p[j] - mup;
    q += d1 * d1; qp += d2 * d2;
  }
  q = wsum64(q); qp = wsum64(qp);
  const float is = rsqrtf(q * (1.f / 512.f) + 1e-5f);
  const float isp = rsqrtf(qp * (1.f / 512.f) + 1e-5f);
  bf16x8 pk;
#pragma unroll
  for (int j = 0; j < 8; ++j) {
    const float wc = w[c0 + j], bc = b[c0 + j];
    const float hv = (v[j] - mu) * is * wc + bc;
    const float hp = first ? 0.f : (p[j] - mup) * isp * wc + bc;
    pk[j] = (short)f2bf(fmaf(hp - hv, coef[c0 + j], hv));
  }
  *(bf16x8*)&kf[idx] = pk;
}

__global__ __launch_bounds__(256) void prep_k(
    float* __restrict__ k, const float* __restrict__ a,
    const float* __restrict__ kkp, const float* __restrict__ kap,
    float* __restrict__ aa, float* __restrict__ bb)
{
  const int m = blockIdx.x * 4 + (threadIdx.x >> 6);
  const int lane = threadIdx.x & 63;
  const int c0 = lane << 3;
  const size_t idx = (size_t)m * CDIM + c0;
  float kv[8], av[8], kp[8], ka[8];
  *(float4*)&kv[0] = *(const float4*)&k[idx];     *(float4*)&kv[4] = *(const float4*)&k[idx + 4];
  *(float4*)&av[0] = *(const float4*)&a[idx];     *(float4*)&av[4] = *(const float4*)&a[idx + 4];
  *(float4*)&kp[0] = *(const float4*)&kkp[c0];    *(float4*)&kp[4] = *(const float4*)&kkp[c0 + 4];
  *(float4*)&ka[0] = *(const float4*)&kap[c0];    *(float4*)&ka[4] = *(const float4*)&kap[c0 + 4];
  float kk[8], ss = 0.f;
#pragma unroll
  for (int j = 0; j < 8; ++j) { kk[j] = kv[j] * kp[j]; ss += kk[j] * kk[j]; }
  ss = gsum8(ss);
  const float rden = 1.f / fmaxf(sqrtf(ss), 1e-12f);
  float oaa[8], obb[8], okk[8];
#pragma unroll
  for (int j = 0; j < 8; ++j) {
    const float kkn = kk[j] * rden;
    oaa[j] = -kkn;
    obb[j] = kkn * av[j];
    okk[j] = kv[j] * (1.f + (av[j] - 1.f) * ka[j]);
  }
  *(float4*)&aa[idx] = *(float4*)&oaa[0]; *(float4*)&aa[idx + 4] = *(float4*)&oaa[4];
  *(float4*)&bb[idx] = *(float4*)&obb[0]; *(float4*)&bb[idx + 4] = *(float4*)&obb[4];
  *(float4*)&k[idx]  = *(float4*)&okk[0]; *(float4*)&k[idx + 4]  = *(float4*)&okk[4];
}

__global__ __launch_bounds__(256) void post_k(
    const float* __restrict__ o, const float* __restrict__ r,
    const float* __restrict__ k, const float* __restrict__ v,
    const float* __restrict__ g, const float* __restrict__ gw,
    const float* __restrict__ gb, const float* __restrict__ rkp,
    ushort_t* __restrict__ og)
{
  const int m = blockIdx.x * 4 + (threadIdx.x >> 6);
  const int lane = threadIdx.x & 63;
  const int c0 = lane << 3;
  const size_t idx = (size_t)m * CDIM + c0;
  float ov[8], rv[8], kv[8], vv[8], gv[8], rp[8];
  *(float4*)&ov[0] = *(const float4*)&o[idx];   *(float4*)&ov[4] = *(const float4*)&o[idx + 4];
  *(float4*)&rv[0] = *(const float4*)&r[idx];   *(float4*)&rv[4] = *(const float4*)&r[idx + 4];
  *(float4*)&kv[0] = *(const float4*)&k[idx];   *(float4*)&kv[4] = *(const float4*)&k[idx + 4];
  *(float4*)&vv[0] = *(const float4*)&v[idx];   *(float4*)&vv[4] = *(const float4*)&v[idx + 4];
  *(float4*)&gv[0] = *(const float4*)&g[idx];   *(float4*)&gv[4] = *(const float4*)&g[idx + 4];
  *(float4*)&rp[0] = *(const float4*)&rkp[c0];  *(float4*)&rp[4] = *(const float4*)&rkp[c0 + 4];
  float s = 0.f, dot = 0.f;
#pragma unroll
  for (int j = 0; j < 8; ++j) { s += ov[j]; dot += rv[j] * kv[j] * rp[j]; }
  s = gsum8(s); dot = gsum8(dot);
  const float mu = s * (1.f / 64.f);
  float q = 0.f;
#pragma unroll
  for (int j = 0; j < 8; ++j) { const float d = ov[j] - mu; q += d * d; }
  q = gsum8(q);
  const float is = rsqrtf(q * (1.f / 64.f) + 64e-5f);
  bf16x8 pk;
#pragma unroll
  for (int j = 0; j < 8; ++j) {
    const float gn = (ov[j] - mu) * is * gw[c0 + j] + gb[c0 + j];
    pk[j] = (short)f2bf((gn + dot * vv[j]) * gv[j]);
  }
  *(bf16x8*)&og[idx] = pk;
}

__global__ __launch_bounds__(512) void ln_final_k(
    const float* __restrict__ x, const float* __restrict__ w,
    const float* __restrict__ b, float* __restrict__ out)
{
  const int m = blockIdx.x, c = threadIdx.x;
  const size_t idx = (size_t)m * CDIM + c;
  const float v = x[idx];
  __shared__ float red[8], red2[8];
  float s = wsum64(v);
  if ((c & 63) == 0) red[c >> 6] = s;
  __syncthreads();
  float tot = 0.f;
#pragma unroll
  for (int u = 0; u < 8; ++u) tot += red[u];
  const float mu = tot * (1.f / 512.f);
  const float dv = v - mu;
  float s2 = wsum64(dv * dv);
  if ((c & 63) == 0) red2[c >> 6] = s2;
  __syncthreads();
  float vt = 0.f;
#pragma unroll
  for (int u = 0; u < 8; ++u) vt += red2[u];
  const float y = dv * rsqrtf(vt * (1.f / 512.f) + 1e-5f) * w[c] + b[c];
  const int bidx = m >> 10, t = m & 1023;
  const int p = t & 127, eb = bidx * 8 + (t >> 7);
  out[((size_t)eb * CDIM + c) * 128 + p] = y;
}

__global__ __launch_bounds__(512) void build_x_k(
    const float* __restrict__ img, const float* __restrict__ pos,
    float* __restrict__ x)
{
  const int m = blockIdx.x, c = threadIdx.x;
  const int bidx = m >> 10, t = m & 1023;
  const int p = t & 127, eb = bidx * 8 + (t >> 7);
  x[(size_t)m * CDIM + c] =
      img[((size_t)eb * CDIM + c) * 128 + p] + pos[(size_t)p * CDIM + c];
}

// ---------------------------------------------------------------------------
// Chunked RWKV7 scan. scan1 (row-split x2): block z handles state rows
// [32z, 32z+32). Thread (rg=tid>>4, cg=tid&15) owns 2 rows x 4 cols.
// Per chunk from S=0/P=I: per step emit o_local, y=P*r; store P,Q at end.
// ---------------------------------------------------------------------------
__global__ __launch_bounds__(256) void scan1_k(
    const float* __restrict__ r, const float* __restrict__ d,
    const float* __restrict__ k, const float* __restrict__ v,
    const float* __restrict__ aa, const float* __restrict__ bb,
    float* __restrict__ P, float* __restrict__ Q,
    float* __restrict__ Y, float* __restrict__ o)
{
  const int ch = blockIdx.x, bh = blockIdx.y;
  const int b = bh >> 3, hh = bh & 7;
  const int tid = threadIdx.x;
  const int rg = tid >> 4, cg = tid & 15;
  const int c0 = cg << 2;
  const int r0 = (blockIdx.z << 5) + (rg << 1);   // 2 rows per thread
  float S[8], Pr[8];
#pragma unroll
  for (int ri = 0; ri < 2; ++ri)
#pragma unroll
    for (int cj = 0; cj < 4; ++cj) {
      S[ri * 4 + cj] = 0.f;
      Pr[ri * 4 + cj] = (r0 + ri == c0 + cj) ? 1.f : 0.f;
    }

  __shared__ float sbuf[3][6 * TB * 64];   // 36 KB
  const size_t base = (size_t)b * TT * CDIM + (size_t)ch * LC * CDIM + hh * 64;
  const float* srcs[6] = {r, d, k, v, aa, bb};
  const int f0 = tid, f1 = tid + 256, f2 = tid + 512;
  const float* gp0 = srcs[f0 >> 7] + base + (size_t)((f0 >> 4) & 7) * CDIM + ((f0 & 15) << 2);
  const float* gp1 = srcs[f1 >> 7] + base + (size_t)((f1 >> 4) & 7) * CDIM + ((f1 & 15) << 2);
  const float* gp2 = srcs[f2 >> 7] + base + (size_t)((f2 >> 4) & 7) * CDIM + ((f2 & 15) << 2);
  const size_t pqbase = ((size_t)(bh * NCH + ch)) * 4096;
  const size_t ybase0 = ((size_t)(bh * NCH + ch)) * (LC * 64);

#define STAGE1(bf_, goff_)                          \
  {                                                 \
    glds16(gp0 + (goff_), &sbuf[bf_][f0 << 2]);     \
    glds16(gp1 + (goff_), &sbuf[bf_][f1 << 2]);     \
    glds16(gp2 + (goff_), &sbuf[bf_][f2 << 2]);     \
  }

#define CGRP1(bf_, g_)                                                          \
  {                                                                             \
    const float* sb0 = sbuf[bf_];                                               \
    const size_t obase = base + (size_t)(g_) * TB * CDIM;                       \
    const size_t ybase = ybase0 + (size_t)(g_) * TB * 64;                       \
    _Pragma("unroll") for (int tt = 0; tt < TB; ++tt) {                         \
      const float* sr  = sb0 + 0 * TB * 64 + tt * 64;                           \
      const float* sd  = sb0 + 1 * TB * 64 + tt * 64;                           \
      const float* sk  = sb0 + 2 * TB * 64 + tt * 64;                           \
      const float* sv  = sb0 + 3 * TB * 64 + tt * 64;                           \
      const float* sa  = sb0 + 4 * TB * 64 + tt * 64;                           \
      const float* sbv = sb0 + 5 * TB * 64 + tt * 64;                           \
      const float4 a4 = *(const float4*)(sa + c0);                              \
      const float4 d4 = *(const float4*)(sd + c0);                              \
      const float4 k4 = *(const float4*)(sk + c0);                              \
      const float4 b4 = *(const float4*)(sbv + c0);                             \
      const float4 r4 = *(const float4*)(sr + c0);                              \
      const float2 v2 = *(const float2*)(sv + r0);                              \
      const float dd[4] = {d4.x, d4.y, d4.z, d4.w};                             \
      const float ak[4] = {a4.x, a4.y, a4.z, a4.w};                             \
      const float kc[4] = {k4.x, k4.y, k4.z, k4.w};                             \
      const float bc2[4] = {b4.x, b4.y, b4.z, b4.w};                            \
      const float rr[4] = {r4.x, r4.y, r4.z, r4.w};                             \
      const float vr[2] = {v2.x, v2.y};                                         \
      float ps[2], pp[2];                                                       \
      _Pragma("unroll") for (int ri = 0; ri < 2; ++ri) {                        \
        ps[ri] = fmaf(S[ri*4+0], ak[0], fmaf(S[ri*4+1], ak[1],                  \
                 fmaf(S[ri*4+2], ak[2], S[ri*4+3] * ak[3])));                   \
        pp[ri] = fmaf(Pr[ri*4+0], ak[0], fmaf(Pr[ri*4+1], ak[1],                \
                 fmaf(Pr[ri*4+2], ak[2], Pr[ri*4+3] * ak[3])));                 \
      }                                                                         \
      _Pragma("unroll") for (int ri = 0; ri < 2; ++ri) {                        \
        ps[ri] = rowsum16(ps[ri]);                                              \
        pp[ri] = rowsum16(pp[ri]);                                              \
      }                                                                         \
      float yv[2], ol[2];                                                       \
      _Pragma("unroll") for (int ri = 0; ri < 2; ++ri) {                        \
        float yacc = 0.f, oacc = 0.f;                                           \
        _Pragma("unroll") for (int cj = 0; cj < 4; ++cj) {                      \
          const float sn = fmaf(S[ri*4+cj], dd[cj],                             \
                           fmaf(ps[ri], bc2[cj], vr[ri] * kc[cj]));             \
          const float pn = fmaf(Pr[ri*4+cj], dd[cj], pp[ri] * bc2[cj]);         \
          S[ri*4+cj] = sn;                                                      \
          Pr[ri*4+cj] = pn;                                                     \
          oacc = fmaf(sn, rr[cj], oacc);                                        \
          yacc = fmaf(pn, rr[cj], yacc);                                        \
        }                                                                       \
        ol[ri] = oacc; yv[ri] = yacc;                                           \
      }                                                                         \
      _Pragma("unroll") for (int ri = 0; ri < 2; ++ri) {                        \
        ol[ri] = rowsum16(ol[ri]);                                              \
        yv[ri] = rowsum16(yv[ri]);                                              \
      }                                                                         \
      if (cg == 0) {                                                            \
        *(float2*)&o[obase + (size_t)tt * CDIM + r0] = make_float2(ol[0], ol[1]); \
        *(float2*)&Y[ybase + (size_t)tt * 64 + r0] = make_float2(yv[0], yv[1]); \
      }                                                                         \
    }                                                                           \
  }

  constexpr int NG = LC / TB;   // 8
  STAGE1(0, 0);
  STAGE1(1, (size_t)TB * CDIM);
  int bc = 0, bs = 2;
  for (int g = 0; g + 1 < NG; ++g) {
    asm volatile("s_waitcnt vmcnt(3)" ::: "memory");
    __builtin_amdgcn_s_barrier();
    if (g + 2 < NG) {
      STAGE1(bs, (size_t)(g + 2) * TB * CDIM);
      bs = (bs == 2) ? 0 : bs + 1;
    }
    CGRP1(bc, g);
    bc = (bc == 2) ? 0 : bc + 1;
  }
  asm volatile("s_waitcnt vmcnt(0)" ::: "memory");
  __builtin_amdgcn_s_barrier();
  CGRP1(bc, NG - 1);
#undef STAGE1
#undef CGRP1

  const size_t ob = pqbase + (size_t)r0 * 64 + c0;
#pragma unroll
  for (int ri = 0; ri < 2; ++ri) {
    *(float4*)&Q[ob + ri * 64] = make_float4(S[ri*4+0], S[ri*4+1], S[ri*4+2], S[ri*4+3]);
    *(float4*)&P[ob + ri * 64] = make_float4(Pr[ri*4+0], Pr[ri*4+1], Pr[ri*4+2], Pr[ri*4+3]);
  }
}

// scan2: sequential chunk composition; P AND Q register-prefetched one
// compose ahead so no global-load latency sits on the critical path.
__global__ __launch_bounds__(512) void scan2_k(
    const float* __restrict__ P, const float* __restrict__ Q,
    float* __restrict__ Sst)
{
  const int tid = threadIdx.x;
  const int f0 = tid << 2;
  const int r0 = tid >> 4;
  const int c0 = (tid & 15) << 2;
  __shared__ float sP[4096];
  __shared__ float sS[4096];
  float4 S0 = {0.f, 0.f, 0.f, 0.f}, S1 = {0.f, 0.f, 0.f, 0.f};
  const size_t cbase = (size_t)blockIdx.x * NCH * 4096;
  float4 pf0 = *(const float4*)&P[cbase + f0];
  float4 pf1 = *(const float4*)&P[cbase + f0 + 2048];
  float4 qf0 = *(const float4*)&Q[cbase + f0];
  float4 qf1 = *(const float4*)&Q[cbase + f0 + 2048];

  for (int c = 0; c < NCH; ++c) {
    const size_t cb = cbase + (size_t)c * 4096;
    *(float4*)&Sst[cb + f0] = S0;
    *(float4*)&Sst[cb + f0 + 2048] = S1;
    __syncthreads();
    *(float4*)&sP[f0] = pf0;  *(float4*)&sP[f0 + 2048] = pf1;
    *(float4*)&sS[f0] = S0;   *(float4*)&sS[f0 + 2048] = S1;
    __syncthreads();
    const float4 q0 = qf0, q1 = qf1;
    if (c + 1 < NCH) {
      pf0 = *(const float4*)&P[cb + 4096 + f0];
      pf1 = *(const float4*)&P[cb + 4096 + f0 + 2048];
      qf0 = *(const float4*)&Q[cb + 4096 + f0];
      qf1 = *(const float4*)&Q[cb + 4096 + f0 + 2048];
    }

    float a00 = 0.f, a01 = 0.f, a02 = 0.f, a03 = 0.f;
    float a10 = 0.f, a11 = 0.f, a12 = 0.f, a13 = 0.f;
    const float* sS0 = &sS[r0 * 64];
    const float* sS1 = &sS[(r0 + 32) * 64];
#pragma unroll
    for (int mm = 0; mm < 64; ++mm) {
      const float4 p4 = *(const float4*)&sP[mm * 64 + c0];
      const float u0 = sS0[mm], u1 = sS1[mm];
      a00 = fmaf(u0, p4.x, a00); a01 = fmaf(u0, p4.y, a01);
      a02 = fmaf(u0, p4.z, a02); a03 = fmaf(u0, p4.w, a03);
      a10 = fmaf(u1, p4.x, a10); a11 = fmaf(u1, p4.y, a11);
      a12 = fmaf(u1, p4.z, a12); a13 = fmaf(u1, p4.w, a13);
    }
    S0.x = a00 + q0.x; S0.y = a01 + q0.y; S0.z = a02 + q0.z; S0.w = a03 + q0.w;
    S1.x = a10 + q1.x; S1.y = a11 + q1.y; S1.z = a12 + q1.z; S1.w = a13 + q1.w;
  }
}

// corr: o[t][i] += sum_j Sst[i][j] * Y[t][j]  (one LC=64 chunk per block).
__global__ __launch_bounds__(256) void corr_k(
    const float* __restrict__ Sst, const float* __restrict__ Y,
    float* __restrict__ o)
{
  const int ch = blockIdx.x, bh = blockIdx.y;
  const int b = bh >> 3, hh = bh & 7;
  const int tid = threadIdx.x;
  __shared__ float ST[64][68];   // ST[j][i] = Sst[i][j]
  __shared__ float Yl[64][68];   // Yl[t][j]
  const size_t cb = ((size_t)(bh * NCH + ch)) * 4096;
#pragma unroll
  for (int u = 0; u < 16; ++u) {
    const int idx = tid + 256 * u;
    ST[idx & 63][idx >> 6] = Sst[cb + idx];
  }
#pragma unroll
  for (int u = 0; u < 4; ++u) {
    const int fi = tid + 256 * u;              // float4 index 0..1023
    *(float4*)&Yl[fi >> 4][(fi & 15) << 2] = *(const float4*)&Y[cb + (size_t)fi * 4];
  }
  __syncthreads();
  const int t = tid >> 2, q = tid & 3, i0 = q << 4;
  f32x4 acc[4];
#pragma unroll
  for (int u = 0; u < 4; ++u) acc[u] = (f32x4){0.f, 0.f, 0.f, 0.f};
  const float* yrow = &Yl[t][0];
#pragma unroll 4
  for (int j = 0; j < 64; ++j) {
    const float yv = yrow[j];
#pragma unroll
    for (int u = 0; u < 4; ++u) {
      const f32x4 s4 = *(const f32x4*)&ST[j][i0 + 4 * u];
      acc[u] = {fmaf(yv, s4[0], acc[u][0]), fmaf(yv, s4[1], acc[u][1]),
                fmaf(yv, s4[2], acc[u][2]), fmaf(yv, s4[3], acc[u][3])};
    }
  }
  const size_t obase = (size_t)b * TT * CDIM + (size_t)ch * LC * CDIM + hh * 64 +
                       (size_t)t * CDIM + i0;
#pragma unroll
  for (int u = 0; u < 4; ++u) {
    float4 cur = *(const float4*)&o[obase + 4 * u];
    cur.x += acc[u][0]; cur.y += acc[u][1]; cur.z += acc[u][2]; cur.w += acc[u][3];
    *(float4*)&o[obase + 4 * u] = cur;
  }
}

// ---------------------------------------------------------------------------
extern "C" void kernel_launch(void* const* d_in, const int* in_sizes, int n_in,
                              void* d_out, int out_size, void* d_ws, size_t ws_size,
                              hipStream_t stream) {
  (void)in_sizes; (void)n_in; (void)out_size; (void)ws_size;
  const float* img  = (const float*)d_in[0];
  const float* pos  = (const float*)d_in[1];
  const float* xm   = (const float*)d_in[2];
  const float* w0   = (const float*)d_in[3];
  const float* w1   = (const float*)d_in[4];
  const float* w2   = (const float*)d_in[5];
  const float* a0   = (const float*)d_in[6];
  const float* a1   = (const float*)d_in[7];
  const float* a2   = (const float*)d_in[8];
  const float* v0   = (const float*)d_in[9];
  const float* v1   = (const float*)d_in[10];
  const float* v2   = (const float*)d_in[11];
  const float* g1   = (const float*)d_in[12];
  const float* g2   = (const float*)d_in[13];
  const float* kkp  = (const float*)d_in[14];
  const float* kap  = (const float*)d_in[15];
  const float* rkp  = (const float*)d_in[16];
  const float* Wr   = (const float*)d_in[17];
  const float* Wk   = (const float*)d_in[18];
  const float* Wv   = (const float*)d_in[19];
  const float* Wo   = (const float*)d_in[20];
  const float* lnxw = (const float*)d_in[21];
  const float* lnxb = (const float*)d_in[22];
  const float* ln1w = (const float*)d_in[23];
  const float* ln1b = (const float*)d_in[24];
  const float* ln2w = (const float*)d_in[25];
  const float* ln2b = (const float*)d_in[26];
  const float* fxk  = (const float*)d_in[27];
  const float* Wkey = (const float*)d_in[28];
  const float* Wval = (const float*)d_in[29];
  const float* lnfw = (const float*)d_in[30];
  const float* lnfb = (const float*)d_in[31];

  float* ws = (float*)d_ws;
  const size_t SZ = (size_t)NTOK * CDIM;   // 2M elements
  float* x   = ws + 0 * SZ;
  float* r_  = ws + 2 * SZ;
  float* dec = ws + 3 * SZ;
  float* k_  = ws + 4 * SZ;
  float* v_  = ws + 5 * SZ;
  float* vf  = ws + 6 * SZ;
  float* a_  = ws + 7 * SZ;
  float* g_  = ws + 8 * SZ;
  float* aa  = ws + 9 * SZ;
  float* bb  = ws + 10 * SZ;
  float* o_  = ws + 11 * SZ;
  float* mixf = ws + 12 * SZ;
  ushort_t* xr = (ushort_t*)mixf;
  ushort_t* xw = xr + SZ;
  ushort_t* xk = xr + 2 * SZ;
  ushort_t* xv = xr + 3 * SZ;
  ushort_t* xa = xr + 4 * SZ;
  ushort_t* xg = xr + 5 * SZ;
  float* Pbuf = mixf;
  float* Qbuf = mixf + SZ;
  float* Sst  = mixf + 2 * SZ;
  ushort_t* tmpb = (ushort_t*)(ws + 15 * SZ);            // 4096 x 288 bf16
  ushort_t* t0b = tmpb;
  ushort_t* t1b = tmpb + (size_t)NTOK * 64;
  ushort_t* t2b = tmpb + (size_t)NTOK * 128;
  ushort_t* t3b = tmpb + (size_t)NTOK * 160;
  ushort_t* tfb  = (ushort_t*)(ws + 15 * SZ + SZ / 2);   // 4096 x 2048 bf16
  float* Ybuf = ws + 16 * SZ;    // aliases tfb interior; dead during time-mix
  ushort_t* ogb  = (ushort_t*)(ws + 17 * SZ + SZ / 2);   // 4096 x 512 bf16
  ushort_t* wb   = (ushort_t*)(ws + 18 * SZ);            // bf16 weights

  const size_t oWr  = 0;
  const size_t oWk  = oWr  + (size_t)8 * 512 * 512;
  const size_t oWv  = oWk  + (size_t)8 * 512 * 512;
  const size_t oWo  = oWv  + (size_t)8 * 512 * 512;
  const size_t oW1  = oWo  + (size_t)8 * 512 * 512;
  const size_t oW2  = oW1  + (size_t)8 * 128 * 512;
  const size_t oA1  = oW2  + (size_t)8 * 512 * 64;
  const size_t oA2  = oA1  + (size_t)8 * 128 * 512;
  const size_t oV1  = oA2  + (size_t)8 * 512 * 64;
  const size_t oV2  = oV1  + (size_t)8 * 128 * 512;
  const size_t oG1  = oV2  + (size_t)8 * 512 * 32;
  const size_t oG2  = oG1  + (size_t)8 * 128 * 512;
  const size_t oKey = oG2  + (size_t)8 * 512 * 128;
  const size_t oVal = oKey + (size_t)8 * 2048 * 512;

#define WPREP(src, dst, K_, N_, NP_) \
  wprep_k<<<dim3((NP_) / 32, (K_) / 32, 8), 256, 0, stream>>>(src, dst, K_, N_, NP_)
  WPREP(Wr,   wb + oWr,  512, 512, 512);
  WPREP(Wk,   wb + oWk,  512, 512, 512);
  WPREP(Wv,   wb + oWv,  512, 512, 512);
  WPREP(Wo,   wb + oWo,  512, 512, 512);
  WPREP(w1,   wb + oW1,  512, 64,  128);
  WPREP(w2,   wb + oW2,  64,  512, 512);
  WPREP(a1,   wb + oA1,  512, 64,  128);
  WPREP(a2,   wb + oA2,  64,  512, 512);
  WPREP(v1,   wb + oV1,  512, 32,  128);
  WPREP(v2,   wb + oV2,  32,  512, 512);
  WPREP(g1,   wb + oG1,  512, 128, 128);
  WPREP(g2,   wb + oG2,  128, 512, 512);
  WPREP(Wkey, wb + oKey, 512, 2048, 2048);
  WPREP(Wval, wb + oVal, 2048, 512, 512);
#undef WPREP

  build_x_k<<<NTOK, 512, 0, stream>>>(img, pos, x);

  for (int l = 0; l < 8; ++l) {
    const size_t lc = (size_t)l * CDIM;
    const float* xml = xm + (size_t)l * 6 * CDIM;
    const ushort_t* bWr = wb + oWr + (size_t)l * 512 * 512;
    const ushort_t* bWk = wb + oWk + (size_t)l * 512 * 512;
    const ushort_t* bWv = wb + oWv + (size_t)l * 512 * 512;
    const ushort_t* bWo = wb + oWo + (size_t)l * 512 * 512;
    const ushort_t* bW1 = wb + oW1 + (size_t)l * 128 * 512;
    const ushort_t* bW2 = wb + oW2 + (size_t)l * 512 * 64;
    const ushort_t* bA1 = wb + oA1 + (size_t)l * 128 * 512;
    const ushort_t* bA2 = wb + oA2 + (size_t)l * 512 * 64;
    const ushort_t* bV1 = wb + oV1 + (size_t)l * 128 * 512;
    const ushort_t* bV2 = wb + oV2 + (size_t)l * 512 * 32;
    const ushort_t* bG1 = wb + oG1 + (size_t)l * 128 * 512;
    const ushort_t* bG2 = wb + oG2 + (size_t)l * 512 * 128;
    const ushort_t* bKy = wb + oKey + (size_t)l * 2048 * 512;
    const ushort_t* bVl = wb + oVal + (size_t)l * 512 * 2048;
    float* vdst = (l == 0) ? vf : v_;

    // ---- time mix ----
    lnmix6_k<<<NTOK / 4, 256, 0, stream>>>(x, ln1w + lc, ln1b + lc, xml,
                                           xr, xw, xk, xv, xa, xg);
    Segs4 qkv;
    qkv.s[0] = {xr, bWr, r_,   0, 0, 512, 512, EPI_NONE, 0};
    qkv.s[1] = {xk, bWk, k_,   0, 0, 512, 512, EPI_NONE, 0};
    qkv.s[2] = {xv, bWv, vdst, 0, 0, 512, 512, EPI_NONE, 0};
    qkv.s[3] = {0, 0, 0, 0, 0, 0, 0, -1, 0};
    ggemm_k<64><<<dim3(NTOK / BM, 8, 3), 256, 0, stream>>>(qkv);

    Segs4 dn;
    dn.s[0] = {xw, bW1, t0b, 0, 0, 64,  512, EPI_TANH, 1};
    dn.s[1] = {xa, bA1, t1b, 0, 0, 64,  512, EPI_NONE, 1};
    dn.s[2] = {xv, bV1, t2b, 0, 0, 32,  512, EPI_NONE, 1};
    dn.s[3] = {xg, bG1, t3b, 0, 0, 128, 512, EPI_SIG,  1};
    ggemm_k<64><<<dim3(NTOK / BM, 2, 4), 256, 0, stream>>>(dn);

    Segs4 up;
    up.s[0] = {t0b, bW2, dec, w0 + lc, 0,  512, 64,  EPI_DECAY, 0};
    up.s[1] = {t1b, bA2, a_,  a0 + lc, 0,  512, 64,  EPI_SIGB,  0};
    up.s[2] = {t2b, bV2, v_,  v0 + lc, vf, 512, 32,  (l > 0) ? EPI_VMIX : -1, 0};
    up.s[3] = {t3b, bG2, g_,  0, 0,        512, 128, EPI_NONE,  0};
    ggemm_k<64><<<dim3(NTOK / BM, 8, 4), 256, 0, stream>>>(up);

    const float* vptr = (l == 0) ? vf : v_;
    prep_k<<<NTOK / 4, 256, 0, stream>>>(k_, a_, kkp + lc, kap + lc, aa, bb);
    scan1_k<<<dim3(NCH, 32, 2), 256, 0, stream>>>(r_, dec, k_, vptr, aa, bb,
                                                  Pbuf, Qbuf, Ybuf, o_);
    scan2_k<<<32, 512, 0, stream>>>(Pbuf, Qbuf, Sst);
    corr_k<<<dim3(NCH, 32), 256, 0, stream>>>(Sst, Ybuf, o_);
    post_k<<<NTOK / 4, 256, 0, stream>>>(o_, r_, k_, vptr, g_, lnxw + lc, lnxb + lc,
                                         rkp + lc, ogb);
    Segs4 wo;
    wo.s[0] = {ogb, bWo, x, 0, 0, 512, 512, EPI_ADD, 0};
    wo.s[1] = wo.s[2] = wo.s[3] = {0, 0, 0, 0, 0, 0, 0, -1, 0};
    ggemm_k<64><<<dim3(NTOK / BM, 8, 1), 256, 0, stream>>>(wo);

    // ---- channel mix ----
    lnmix1_k<<<NTOK / 4, 256, 0, stream>>>(x, ln2w + lc, ln2b + lc, fxk + lc, xr);
    Segs4 f1;
    f1.s[0] = {xr, bKy, tfb, 0, 0, 2048, 512, EPI_RELU2, 1};
    f1.s[1] = f1.s[2] = f1.s[3] = {0, 0, 0, 0, 0, 0, 0, -1, 0};
    ggemm_k<64><<<dim3(NTOK / BM, 32, 1), 256, 0, stream>>>(f1);
    Segs4 f2;
    f2.s[0] = {tfb, bVl, x, 0, 0, 512, 2048, EPI_ADD, 0};
    f2.s[1] = f2.s[2] = f2.s[3] = {0, 0, 0, 0, 0, 0, 0, -1, 0};
    ggemm_k<64><<<dim3(NTOK / BM, 8, 1), 256, 0, stream>>>(f2);
  }

  ln_final_k<<<NTOK, 512, 0, stream>>>(x, lnfw, lnfb, (float*)d_out);
}